// Round 2
// baseline (12610.234 us; speedup 1.0000x reference)
//
#include <hip/hip_runtime.h>

typedef _Float16 f16;
typedef _Float16 f16x8 __attribute__((ext_vector_type(8)));
typedef float f32x4 __attribute__((ext_vector_type(4)));

#define B_ 512
#define T_ 128
#define I_ 64
#define H_ 512
#define O_ 64
#define L_ 300
#define OUTSTR (L_*O_)   // 19200 floats per batch row of d_out
#define NBLK 256

// ---------------------------------------------------------------------------
// Prologue kernels (verified in R0): convert x to fp16 [t][b][i], build
// fused/packed weights. Packed B layout (MFMA 16x16x32 f16 B-fragment order):
//   flat = ((ntile_global*KSTEPS + kstep)*64 + lane)*8 + elem
//   value = W[k][col] with k = kstep*32 + (lane>>4)*8 + elem, col = lane&15
// ---------------------------------------------------------------------------

__global__ void k_zero_h(f16* h) {
  int i = blockIdx.x*256 + threadIdx.x;
  if (i < B_*H_) h[i] = (f16)0.f;
}

__global__ void k_cvt_x(const float* __restrict__ x, f16* __restrict__ x16) {
  int p = blockIdx.x*256 + threadIdx.x;   // p = (t*512 + b)*64 + i
  if (p >= T_*B_*I_) return;
  int i = p & 63;
  int b = (p >> 6) & 511;
  int t = p >> 15;
  x16[p] = (f16)x[((size_t)b*T_ + t)*I_ + i];
}

// Wf[j3][k] = sum_o Wo[o][k] * Wih[j3][o]   (the folded y->gi path)
__global__ void k_fuse(const float* __restrict__ Wo, const float* __restrict__ Wih,
                       float* __restrict__ Wf) {
  int p = blockIdx.x*256 + threadIdx.x;
  if (p >= 1536*512) return;
  int k = p & 511, j3 = p >> 9;
  float s = 0.f;
  for (int o = 0; o < 64; ++o)
    s += Wo[(size_t)o*H_ + k] * Wih[(size_t)j3*I_ + o];
  Wf[p] = s;
}

// bf[j3] = sum_o bo[o] * Wih[j3][o]
__global__ void k_bf(const float* __restrict__ bo, const float* __restrict__ Wih,
                     float* __restrict__ bf) {
  int j3 = blockIdx.x*256 + threadIdx.x;
  if (j3 >= 1536) return;
  float s = 0.f;
  for (int o = 0; o < 64; ++o) s += bo[o]*Wih[(size_t)j3*I_ + o];
  bf[j3] = s;
}

// Encoder packed weights: 32 groups x 4 ntiles {r,z,hn,inn}, K=576 ([h|x]).
__global__ void k_pack_enc(const float* __restrict__ Whh, const float* __restrict__ Wih,
                           f16* __restrict__ We) {
  int p = blockIdx.x*256 + threadIdx.x;
  if (p >= 128*18*512) return;
  int i  = p & 7;
  int l  = (p >> 3) & 63;
  int ks = (p >> 9) % 18;
  int ntg = p / (18*512);
  int g = ntg >> 2, nti = ntg & 3;
  int c = l & 15;
  int j = g*16 + c;
  int k = ks*32 + ((l>>4)<<3) + i;
  float v = 0.f;
  if (nti == 0)      v = (k < 512) ? Whh[(size_t)j*H_ + k]          : Wih[(size_t)j*I_ + (k-512)];
  else if (nti == 1) v = (k < 512) ? Whh[(size_t)(512+j)*H_ + k]    : Wih[(size_t)(512+j)*I_ + (k-512)];
  else if (nti == 2) v = (k < 512) ? Whh[(size_t)(1024+j)*H_ + k]   : 0.f;
  else               v = (k >= 512)? Wih[(size_t)(1024+j)*I_ + (k-512)] : 0.f;
  We[p] = (f16)v;
}

// Decoder packed weights: 32 groups x 5 ntiles {r+f, z+f, hn, inn_f, y}, K=512.
__global__ void k_pack_dec(const float* __restrict__ Whh, const float* __restrict__ Wo,
                           const float* __restrict__ Wf, f16* __restrict__ Wd) {
  int p = blockIdx.x*256 + threadIdx.x;
  if (p >= 160*16*512) return;
  int i  = p & 7;
  int l  = (p >> 3) & 63;
  int ks = (p >> 9) & 15;
  int ntg = p >> 13;
  int g = ntg/5, nti = ntg%5;
  int c = l & 15;
  int j = g*16 + c;
  int k = ks*32 + ((l>>4)<<3) + i;
  float v;
  if (nti == 0)      v = Whh[(size_t)j*H_+k]        + Wf[(size_t)j*512 + k];
  else if (nti == 1) v = Whh[(size_t)(512+j)*H_+k]  + Wf[(size_t)(512+j)*512 + k];
  else if (nti == 2) v = Whh[(size_t)(1024+j)*H_+k];
  else if (nti == 3) v = Wf[(size_t)(1024+j)*512 + k];
  else               v = (c < 2) ? Wo[(size_t)(2*g+c)*H_ + k] : 0.f;
  Wd[p] = (f16)v;
}

__global__ void k_bias_enc(const float* __restrict__ bih, const float* __restrict__ bhh,
                           float* __restrict__ be) {
  int p = blockIdx.x*256 + threadIdx.x;
  if (p >= 2048) return;
  int c = p & 15, ntg = p >> 4, g = ntg >> 2, nti = ntg & 3, j = g*16 + c;
  float v;
  if (nti == 0)      v = bih[j] + bhh[j];
  else if (nti == 1) v = bih[512+j] + bhh[512+j];
  else if (nti == 2) v = bhh[1024+j];
  else               v = bih[1024+j];
  be[p] = v;
}

__global__ void k_bias_dec(const float* __restrict__ bih, const float* __restrict__ bhh,
                           const float* __restrict__ bo, const float* __restrict__ bf,
                           float* __restrict__ bd) {
  int p = blockIdx.x*256 + threadIdx.x;
  if (p >= 2560) return;
  int c = p & 15, ntg = p >> 4, g = ntg/5, nti = ntg%5, j = g*16 + c;
  float v;
  if (nti == 0)      v = bih[j] + bhh[j] + bf[j];
  else if (nti == 1) v = bih[512+j] + bhh[512+j] + bf[512+j];
  else if (nti == 2) v = bhh[1024+j];
  else if (nti == 3) v = bih[1024+j] + bf[1024+j];
  else               v = (c < 2) ? bo[2*g+c] : 0.f;
  bd[p] = v;
}

// ---------------------------------------------------------------------------
// Persistent kernel: 256 blocks (1/CU), 4 waves each. Weights staged in LDS
// ONCE per phase; 427 steps separated by a device-scope grid barrier.
// Block (g = bid&31, bm = bid>>5) owns output tile rows [64bm,+64) x h-cols
// [16g,+16) (all 4/5 gate ntiles locally -> gate fusion in registers).
// h ping-pongs between h0/h1; single barrier per step is sufficient because
// all step-t reads complete (vmcnt drained at __syncthreads) before arrive.
// ---------------------------------------------------------------------------

__device__ __forceinline__ float sigmoidf_(float x){ return 1.f/(1.f + __expf(-x)); }

__device__ __forceinline__ void gbar(unsigned* bar, unsigned target) {
  __syncthreads();                       // all waves' loads/stores drained (vmcnt 0)
  if (threadIdx.x == 0) {
    __threadfence();                     // release: flush this XCD's L2 to LLC
    unsigned old = __hip_atomic_fetch_add(&bar[0], 1u, __ATOMIC_ACQ_REL,
                                          __HIP_MEMORY_SCOPE_AGENT);
    if (old == NBLK-1u) {
      __hip_atomic_store(&bar[0], 0u, __ATOMIC_RELAXED, __HIP_MEMORY_SCOPE_AGENT);
      __hip_atomic_store(&bar[1], target, __ATOMIC_RELEASE, __HIP_MEMORY_SCOPE_AGENT);
    } else {
      while (__hip_atomic_load(&bar[1], __ATOMIC_RELAXED,
                               __HIP_MEMORY_SCOPE_AGENT) < target) {
        __builtin_amdgcn_s_sleep(1);
      }
    }
    __threadfence();                     // acquire: invalidate L1/L2 stale lines
  }
  __syncthreads();
}

#define MFMA16(a,b,acc) __builtin_amdgcn_mfma_f32_16x16x32_f16(a, b, acc, 0, 0, 0)

__global__ __launch_bounds__(256, 1) void k_persist(
    const f16* __restrict__ x16, const f16* __restrict__ We,
    const f16* __restrict__ Wd, const float* __restrict__ be,
    const float* __restrict__ bd, f16* __restrict__ h0, f16* __restrict__ h1,
    float* __restrict__ out, unsigned* bar) {
  __shared__ f16 lds[32768];             // 64 KiB: 4 ntiles x 16 ksteps x 1KB
  const int tid = threadIdx.x, w = tid >> 6, lane = tid & 63;
  const int g = blockIdx.x & 31, bm = blockIdx.x >> 5;
  const int c = lane & 15, rq = lane >> 4;
  const int row0 = bm*64 + w*16 + c;     // A-fragment row for this lane
  const int j = g*16 + c;                // h column this lane's epilogue owns
  unsigned target = 0;

  // ======== encoder phase: stage h-part (K=512) weights once ========
  for (int it = 0; it < 16; ++it) {
    int idx = it*256 + tid;              // 16B units 0..4095
    int nt = idx >> 10, r = idx & 1023;
    *(f16x8*)((char*)lds + (size_t)idx*16) =
        *(const f16x8*)((const char*)We + (size_t)(g*4+nt)*18432 + (size_t)r*16);
  }
  f16x8 bx0,bx1,bx2,bx3,bx4,bx5,bx6,bx7; // x-part (ks 16,17) B-frags in regs
  {
    const char* base = (const char*)We + (size_t)lane*16 + 16*1024;
    bx0 = *(const f16x8*)(base + (size_t)(g*4+0)*18432);
    bx1 = *(const f16x8*)(base + (size_t)(g*4+1)*18432);
    bx2 = *(const f16x8*)(base + (size_t)(g*4+2)*18432);
    bx3 = *(const f16x8*)(base + (size_t)(g*4+3)*18432);
    bx4 = *(const f16x8*)(base + (size_t)(g*4+0)*18432 + 1024);
    bx5 = *(const f16x8*)(base + (size_t)(g*4+1)*18432 + 1024);
    bx6 = *(const f16x8*)(base + (size_t)(g*4+2)*18432 + 1024);
    bx7 = *(const f16x8*)(base + (size_t)(g*4+3)*18432 + 1024);
  }
  float br = be[(g*4+0)*16+c], bz = be[(g*4+1)*16+c];
  float bh = be[(g*4+2)*16+c], bi = be[(g*4+3)*16+c];
  __syncthreads();

  for (int t = 0; t < T_; ++t) {
    const f16* hin  = (t & 1) ? h1 : h0;
    f16*       hout = (t & 1) ? h0 : h1;
    const f16* xt = x16 + (size_t)t*B_*I_;
    f32x4 a0={},a1={},a2={},a3={};
    #pragma unroll
    for (int ks = 0; ks < 16; ++ks) {
      f16x8 a = *(const f16x8*)(hin + (size_t)row0*H_ + ks*32 + (rq<<3));
      a0 = MFMA16(a, *(const f16x8*)(lds + (0*16+ks)*512 + lane*8), a0);
      a1 = MFMA16(a, *(const f16x8*)(lds + (1*16+ks)*512 + lane*8), a1);
      a2 = MFMA16(a, *(const f16x8*)(lds + (2*16+ks)*512 + lane*8), a2);
      a3 = MFMA16(a, *(const f16x8*)(lds + (3*16+ks)*512 + lane*8), a3);
    }
    {
      f16x8 ax = *(const f16x8*)(xt + (size_t)row0*I_ + (rq<<3));
      a0 = MFMA16(ax, bx0, a0); a1 = MFMA16(ax, bx1, a1);
      a2 = MFMA16(ax, bx2, a2); a3 = MFMA16(ax, bx3, a3);
      f16x8 ay = *(const f16x8*)(xt + (size_t)row0*I_ + 32 + (rq<<3));
      a0 = MFMA16(ay, bx4, a0); a1 = MFMA16(ay, bx5, a1);
      a2 = MFMA16(ay, bx6, a2); a3 = MFMA16(ay, bx7, a3);
    }
    #pragma unroll
    for (int i = 0; i < 4; ++i) {
      int row = bm*64 + w*16 + rq*4 + i;
      float r = sigmoidf_(a0[i] + br);
      float z = sigmoidf_(a1[i] + bz);
      float n = tanhf((a3[i] + bi) + r*(a2[i] + bh));
      float hp = (float)hin[(size_t)row*H_ + j];
      hout[(size_t)row*H_ + j] = (f16)((1.f - z)*n + z*hp);
    }
    gbar(bar, ++target);
  }

  // ======== decoder phase: restage gate ntiles, y-ntile in regs ========
  for (int it = 0; it < 16; ++it) {
    int idx = it*256 + tid;
    int nt = idx >> 10, r = idx & 1023;
    *(f16x8*)((char*)lds + (size_t)idx*16) =
        *(const f16x8*)((const char*)Wd + (size_t)(g*5+nt)*16384 + (size_t)r*16);
  }
  f16x8 yb[16];
  #pragma unroll
  for (int ks = 0; ks < 16; ++ks)
    yb[ks] = *(const f16x8*)((const char*)Wd + (size_t)(g*5+4)*16384
                             + (size_t)ks*1024 + (size_t)lane*16);
  float dr = bd[(g*5+0)*16+c], dz = bd[(g*5+1)*16+c];
  float dh = bd[(g*5+2)*16+c], di = bd[(g*5+3)*16+c], dy = bd[(g*5+4)*16+c];
  __syncthreads();

  for (int d = 0; d < L_-1; ++d) {
    const f16* hin  = (d & 1) ? h1 : h0;
    f16*       hout = (d & 1) ? h0 : h1;
    f32x4 a0={},a1={},a2={},a3={},a4={};
    #pragma unroll
    for (int ks = 0; ks < 16; ++ks) {
      f16x8 a = *(const f16x8*)(hin + (size_t)row0*H_ + ks*32 + (rq<<3));
      a0 = MFMA16(a, *(const f16x8*)(lds + (0*16+ks)*512 + lane*8), a0);
      a1 = MFMA16(a, *(const f16x8*)(lds + (1*16+ks)*512 + lane*8), a1);
      a2 = MFMA16(a, *(const f16x8*)(lds + (2*16+ks)*512 + lane*8), a2);
      a3 = MFMA16(a, *(const f16x8*)(lds + (3*16+ks)*512 + lane*8), a3);
      a4 = MFMA16(a, yb[ks], a4);
    }
    float* yo = out + (size_t)d*O_;
    #pragma unroll
    for (int i = 0; i < 4; ++i) {
      int row = bm*64 + w*16 + rq*4 + i;
      float r = sigmoidf_(a0[i] + dr);
      float z = sigmoidf_(a1[i] + dz);
      float n = tanhf((a3[i] + di) + r*(a2[i] + dh));
      float hp = (float)hin[(size_t)row*H_ + j];
      hout[(size_t)row*H_ + j] = (f16)((1.f - z)*n + z*hp);
      if (c < 2) yo[(size_t)row*OUTSTR + 2*g + c] = a4[i] + dy;
    }
    gbar(bar, ++target);
  }

  // ======== final y projection from h1 (written by d=298) ========
  {
    f32x4 a4 = {};
    #pragma unroll
    for (int ks = 0; ks < 16; ++ks) {
      f16x8 a = *(const f16x8*)(h1 + (size_t)row0*H_ + ks*32 + (rq<<3));
      a4 = MFMA16(a, yb[ks], a4);
    }
    if (c < 2) {
      #pragma unroll
      for (int i = 0; i < 4; ++i) {
        int row = bm*64 + w*16 + rq*4 + i;
        out[(size_t)row*OUTSTR + (size_t)(L_-1)*O_ + 2*g + c] = a4[i] + dy;
      }
    }
  }
}

// ---------------------------------------------------------------------------

extern "C" void kernel_launch(void* const* d_in, const int* in_sizes, int n_in,
                              void* d_out, int out_size, void* d_ws, size_t ws_size,
                              hipStream_t stream) {
  (void)in_sizes; (void)n_in; (void)out_size; (void)ws_size;
  const float* x   = (const float*)d_in[0];
  const float* Wih = (const float*)d_in[1];
  const float* Whh = (const float*)d_in[2];
  const float* bih = (const float*)d_in[3];
  const float* bhh = (const float*)d_in[4];
  const float* Wo  = (const float*)d_in[5];
  const float* bo  = (const float*)d_in[6];
  float* out = (float*)d_out;

  char* ws = (char*)d_ws;
  size_t off = 0;
  auto alloc = [&](size_t bytes) {
    char* p = ws + off;
    off += (bytes + 255) & ~(size_t)255;
    return p;
  };
  f16*   x16 = (f16*)  alloc((size_t)T_*B_*I_*2);      // 8.39 MB, [t][b][i]
  f16*   hA  = (f16*)  alloc((size_t)B_*H_*2);
  f16*   hB  = (f16*)  alloc((size_t)B_*H_*2);
  f16*   We  = (f16*)  alloc((size_t)128*18*512*2);    // enc packed (K=576,N=2048)
  f16*   Wd  = (f16*)  alloc((size_t)160*16*512*2);    // dec packed (K=512,N=2560)
  float* Wf  = (float*)alloc((size_t)1536*512*4);      // fused Wo.T@Wih.T
  float* be  = (float*)alloc(2048*4);
  float* bd  = (float*)alloc(2560*4);
  float* bf  = (float*)alloc(1536*4);
  unsigned* bar = (unsigned*)alloc(256);

  hipMemsetAsync(bar, 0, 16, stream);
  hipLaunchKernelGGL(k_zero_h,   dim3((B_*H_+255)/256),     dim3(256), 0, stream, hA);
  hipLaunchKernelGGL(k_cvt_x,    dim3((T_*B_*I_+255)/256),  dim3(256), 0, stream, x, x16);
  hipLaunchKernelGGL(k_fuse,     dim3(1536*512/256),        dim3(256), 0, stream, Wo, Wih, Wf);
  hipLaunchKernelGGL(k_bf,       dim3(6),                   dim3(256), 0, stream, bo, Wih, bf);
  hipLaunchKernelGGL(k_pack_enc, dim3(128*18*512/256),      dim3(256), 0, stream, Whh, Wih, We);
  hipLaunchKernelGGL(k_pack_dec, dim3(160*16*512/256),      dim3(256), 0, stream, Whh, Wo, Wf, Wd);
  hipLaunchKernelGGL(k_bias_enc, dim3(8),                   dim3(256), 0, stream, bih, bhh, be);
  hipLaunchKernelGGL(k_bias_dec, dim3(10),                  dim3(256), 0, stream, bih, bhh, bo, bf, bd);

  hipLaunchKernelGGL(k_persist, dim3(NBLK), dim3(256), 0, stream,
                     x16, We, Wd, be, bd, hA, hB, out, bar);
}

// Round 4
// 2846.640 us; speedup vs baseline: 4.4299x; 4.4299x over previous
//
#include <hip/hip_runtime.h>

typedef _Float16 f16;
typedef _Float16 f16x8 __attribute__((ext_vector_type(8)));
typedef float f32x4 __attribute__((ext_vector_type(4)));

#define B_ 512
#define T_ 128
#define I_ 64
#define H_ 512
#define O_ 64
#define L_ 300
#define OUTSTR (L_*O_)
#define NBLK 256

// ---------------------------------------------------------------------------
// Prologue kernels (verified R0/R1). Packed B layout (MFMA 16x16x32 f16):
//   flat = ((ntile_global*KSTEPS + kstep)*64 + lane)*8 + elem
//   value = W[k][col], k = kstep*32 + (lane>>4)*8 + elem, col = lane&15
// ---------------------------------------------------------------------------

__global__ void k_zero_h(f16* h) {
  int i = blockIdx.x*256 + threadIdx.x;
  if (i < B_*H_) h[i] = (f16)0.f;
}

__global__ void k_cvt_x(const float* __restrict__ x, f16* __restrict__ x16) {
  int p = blockIdx.x*256 + threadIdx.x;
  if (p >= T_*B_*I_) return;
  int i = p & 63, b = (p >> 6) & 511, t = p >> 15;
  x16[p] = (f16)x[((size_t)b*T_ + t)*I_ + i];
}

__global__ void k_fuse(const float* __restrict__ Wo, const float* __restrict__ Wih,
                       float* __restrict__ Wf) {
  int p = blockIdx.x*256 + threadIdx.x;
  if (p >= 1536*512) return;
  int k = p & 511, j3 = p >> 9;
  float s = 0.f;
  for (int o = 0; o < 64; ++o) s += Wo[(size_t)o*H_ + k] * Wih[(size_t)j3*I_ + o];
  Wf[p] = s;
}

__global__ void k_bf(const float* __restrict__ bo, const float* __restrict__ Wih,
                     float* __restrict__ bf) {
  int j3 = blockIdx.x*256 + threadIdx.x;
  if (j3 >= 1536) return;
  float s = 0.f;
  for (int o = 0; o < 64; ++o) s += bo[o]*Wih[(size_t)j3*I_ + o];
  bf[j3] = s;
}

__global__ void k_pack_enc(const float* __restrict__ Whh, const float* __restrict__ Wih,
                           f16* __restrict__ We) {
  int p = blockIdx.x*256 + threadIdx.x;
  if (p >= 128*18*512) return;
  int i = p & 7, l = (p >> 3) & 63, ks = (p >> 9) % 18, ntg = p / (18*512);
  int g = ntg >> 2, nti = ntg & 3, c = l & 15;
  int j = g*16 + c, k = ks*32 + ((l>>4)<<3) + i;
  float v = 0.f;
  if (nti == 0)      v = (k < 512) ? Whh[(size_t)j*H_ + k]        : Wih[(size_t)j*I_ + (k-512)];
  else if (nti == 1) v = (k < 512) ? Whh[(size_t)(512+j)*H_ + k]  : Wih[(size_t)(512+j)*I_ + (k-512)];
  else if (nti == 2) v = (k < 512) ? Whh[(size_t)(1024+j)*H_ + k] : 0.f;
  else               v = (k >= 512)? Wih[(size_t)(1024+j)*I_ + (k-512)] : 0.f;
  We[p] = (f16)v;
}

__global__ void k_pack_dec(const float* __restrict__ Whh, const float* __restrict__ Wo,
                           const float* __restrict__ Wf, f16* __restrict__ Wd) {
  int p = blockIdx.x*256 + threadIdx.x;
  if (p >= 160*16*512) return;
  int i = p & 7, l = (p >> 3) & 63, ks = (p >> 9) & 15, ntg = p >> 13;
  int g = ntg/5, nti = ntg%5, c = l & 15;
  int j = g*16 + c, k = ks*32 + ((l>>4)<<3) + i;
  float v;
  if (nti == 0)      v = Whh[(size_t)j*H_+k]       + Wf[(size_t)j*512 + k];
  else if (nti == 1) v = Whh[(size_t)(512+j)*H_+k] + Wf[(size_t)(512+j)*512 + k];
  else if (nti == 2) v = Whh[(size_t)(1024+j)*H_+k];
  else if (nti == 3) v = Wf[(size_t)(1024+j)*512 + k];
  else               v = (c < 2) ? Wo[(size_t)(2*g+c)*H_ + k] : 0.f;
  Wd[p] = (f16)v;
}

__global__ void k_bias_enc(const float* __restrict__ bih, const float* __restrict__ bhh,
                           float* __restrict__ be) {
  int p = blockIdx.x*256 + threadIdx.x;
  if (p >= 2048) return;
  int c = p & 15, ntg = p >> 4, g = ntg >> 2, nti = ntg & 3, j = g*16 + c;
  float v;
  if (nti == 0)      v = bih[j] + bhh[j];
  else if (nti == 1) v = bih[512+j] + bhh[512+j];
  else if (nti == 2) v = bhh[1024+j];
  else               v = bih[1024+j];
  be[p] = v;
}

__global__ void k_bias_dec(const float* __restrict__ bih, const float* __restrict__ bhh,
                           const float* __restrict__ bo, const float* __restrict__ bf,
                           float* __restrict__ bd) {
  int p = blockIdx.x*256 + threadIdx.x;
  if (p >= 2560) return;
  int c = p & 15, ntg = p >> 4, g = ntg/5, nti = ntg%5, j = g*16 + c;
  float v;
  if (nti == 0)      v = bih[j] + bhh[j] + bf[j];
  else if (nti == 1) v = bih[512+j] + bhh[512+j] + bf[512+j];
  else if (nti == 2) v = bhh[1024+j];
  else if (nti == 3) v = bih[1024+j] + bf[1024+j];
  else               v = (c < 2) ? bo[2*g+c] : 0.f;
  bd[p] = v;
}

// ---------------------------------------------------------------------------
// LLC-coherent h exchange: stores write-through to LLC (sc0 sc1), loads bypass
// L1/L2 (sc0 sc1). No fences, no wbl2/inv. Correct for ANY block->XCD map.
// ---------------------------------------------------------------------------

__device__ __forceinline__ float sigmoidf_(float x){ return 1.f/(1.f + __expf(-x)); }
__device__ __forceinline__ float tanhf_(float x){ return 1.f - 2.f/(__expf(2.f*x) + 1.f); }

__device__ __forceinline__ f16x8 ldC(const f16* p) {     // coherent 16B load
  f16x8 r;
  asm volatile("global_load_dwordx4 %0, %1, off sc0 sc1" : "=v"(r) : "v"(p));
  return r;
}
__device__ __forceinline__ f16x8 ldP(const f16* p) {     // read-only (x16), cached
  f16x8 r;
  asm volatile("global_load_dwordx4 %0, %1, off" : "=v"(r) : "v"(p));
  return r;
}
__device__ __forceinline__ unsigned ldC2(const f16* p) { // coherent 2B load
  unsigned r;
  asm volatile("global_load_ushort %0, %1, off sc0 sc1" : "=v"(r) : "v"(p));
  return r;
}
__device__ __forceinline__ void stC2(f16* p, float v) {  // coherent 2B store
  f16 h = (f16)v;
  unsigned b = (unsigned)__builtin_bit_cast(unsigned short, h);
  asm volatile("global_store_short %0, %1, off sc0 sc1" :: "v"(p), "v"(b) : "memory");
}
// Wait for all outstanding asm vmem loads, then fence the scheduler so MFMAs
// (register-only, invisible to the "memory" clobber) cannot hoist above.
__device__ __forceinline__ void vwait0() {
  asm volatile("s_waitcnt vmcnt(0)" ::: "memory");
  __builtin_amdgcn_sched_barrier(0);
}

// Grid barrier: RELAXED AGENT atomics only (no fences -> no wbl2/inv).
// flags: 256 x 64B-padded; go: 8 x 64B-padded replicas.
__device__ __forceinline__ void gbar(unsigned* __restrict__ flags,
                                     unsigned* __restrict__ go,
                                     int bid, unsigned tgt) {
  // ALL waves drain their (inline-asm) stores before arriving: guarantees h
  // writes are LLC-visible before this block's flag is raised.
  asm volatile("s_waitcnt vmcnt(0)" ::: "memory");
  __syncthreads();
  const int tid = threadIdx.x;
  if (bid == 0) {
    if (tid < 64) {
      if (tid == 0)
        __hip_atomic_store(&flags[0], tgt, __ATOMIC_RELAXED, __HIP_MEMORY_SCOPE_AGENT);
      unsigned v0, v1, v2, v3;
      do {
        v0 = __hip_atomic_load(&flags[(tid      )*16], __ATOMIC_RELAXED, __HIP_MEMORY_SCOPE_AGENT);
        v1 = __hip_atomic_load(&flags[(tid +  64)*16], __ATOMIC_RELAXED, __HIP_MEMORY_SCOPE_AGENT);
        v2 = __hip_atomic_load(&flags[(tid + 128)*16], __ATOMIC_RELAXED, __HIP_MEMORY_SCOPE_AGENT);
        v3 = __hip_atomic_load(&flags[(tid + 192)*16], __ATOMIC_RELAXED, __HIP_MEMORY_SCOPE_AGENT);
      } while (!__all(v0 >= tgt && v1 >= tgt && v2 >= tgt && v3 >= tgt));
      if (tid < 8)
        __hip_atomic_store(&go[tid*16], tgt, __ATOMIC_RELAXED, __HIP_MEMORY_SCOPE_AGENT);
    }
  } else {
    if (tid == 0) {
      __hip_atomic_store(&flags[bid*16], tgt, __ATOMIC_RELAXED, __HIP_MEMORY_SCOPE_AGENT);
      while (__hip_atomic_load(&go[(bid & 7)*16], __ATOMIC_RELAXED,
                               __HIP_MEMORY_SCOPE_AGENT) < tgt)
        __builtin_amdgcn_s_sleep(2);
    }
  }
  __syncthreads();
}

#define MFMA16(a,b,acc) __builtin_amdgcn_mfma_f32_16x16x32_f16(a, b, acc, 0, 0, 0)

__global__ __launch_bounds__(256, 1) void k_persist(
    const f16* __restrict__ x16, const f16* __restrict__ We,
    const f16* __restrict__ Wd, const float* __restrict__ be,
    const float* __restrict__ bd, f16* __restrict__ h0, f16* __restrict__ h1,
    float* __restrict__ out, unsigned* __restrict__ flags,
    unsigned* __restrict__ go) {
  __shared__ f16 lds[32768];               // 64 KiB: 4 ntiles x 16 ksteps x 1KB
  const int tid = threadIdx.x, bid = blockIdx.x, w = tid >> 6, lane = tid & 63;
  const int g = bid & 31, bm = bid >> 5;   // col-group, row-slab
  const int c = lane & 15, rq = lane >> 4;
  const int row0 = bm*64 + w*16 + c;       // A-fragment row
  const int rowb = bm*64 + w*16 + rq*4;    // C/D row base
  const int j = g*16 + c;

  // ---- encoder: stage K=512 h-part weights to LDS once; x-part in regs ----
  for (int it = 0; it < 16; ++it) {
    int idx = it*256 + tid;
    int nt = idx >> 10, r = idx & 1023;
    *(f16x8*)((char*)lds + (size_t)idx*16) =
        *(const f16x8*)((const char*)We + (size_t)(g*4+nt)*18432 + (size_t)r*16);
  }
  f16x8 bx0,bx1,bx2,bx3,bx4,bx5,bx6,bx7;
  {
    const char* base = (const char*)We + (size_t)lane*16 + 16*1024;
    bx0 = *(const f16x8*)(base + (size_t)(g*4+0)*18432);
    bx1 = *(const f16x8*)(base + (size_t)(g*4+1)*18432);
    bx2 = *(const f16x8*)(base + (size_t)(g*4+2)*18432);
    bx3 = *(const f16x8*)(base + (size_t)(g*4+3)*18432);
    bx4 = *(const f16x8*)(base + (size_t)(g*4+0)*18432 + 1024);
    bx5 = *(const f16x8*)(base + (size_t)(g*4+1)*18432 + 1024);
    bx6 = *(const f16x8*)(base + (size_t)(g*4+2)*18432 + 1024);
    bx7 = *(const f16x8*)(base + (size_t)(g*4+3)*18432 + 1024);
  }
  float br = be[(g*4+0)*16+c], bz = be[(g*4+1)*16+c];
  float bh = be[(g*4+2)*16+c], bi = be[(g*4+3)*16+c];
  __syncthreads();

  unsigned s = 0;   // global step index 0..426
  for (int t = 0; t < T_; ++t, ++s) {
    const f16* hin  = (t & 1) ? h1 : h0;
    f16*       hout = (t & 1) ? h0 : h1;
    const f16* xt = x16 + (size_t)t*B_*I_;
    f16x8 ha[16];
    #pragma unroll
    for (int ks = 0; ks < 16; ++ks)
      ha[ks] = ldC(hin + (size_t)row0*H_ + ks*32 + (rq<<3));
    f16x8 ax = ldP(xt + (size_t)row0*I_ + (rq<<3));
    f16x8 ay = ldP(xt + (size_t)row0*I_ + 32 + (rq<<3));
    unsigned hp[4];
    #pragma unroll
    for (int i = 0; i < 4; ++i)
      hp[i] = ldC2(hin + (size_t)(rowb+i)*H_ + j);
    vwait0();
    f32x4 a0={},a1={},a2={},a3={};
    #pragma unroll
    for (int ks = 0; ks < 16; ++ks) {
      a0 = MFMA16(ha[ks], *(const f16x8*)(lds + (0*16+ks)*512 + lane*8), a0);
      a1 = MFMA16(ha[ks], *(const f16x8*)(lds + (1*16+ks)*512 + lane*8), a1);
      a2 = MFMA16(ha[ks], *(const f16x8*)(lds + (2*16+ks)*512 + lane*8), a2);
      a3 = MFMA16(ha[ks], *(const f16x8*)(lds + (3*16+ks)*512 + lane*8), a3);
    }
    a0 = MFMA16(ax, bx0, a0); a1 = MFMA16(ax, bx1, a1);
    a2 = MFMA16(ax, bx2, a2); a3 = MFMA16(ax, bx3, a3);
    a0 = MFMA16(ay, bx4, a0); a1 = MFMA16(ay, bx5, a1);
    a2 = MFMA16(ay, bx6, a2); a3 = MFMA16(ay, bx7, a3);
    #pragma unroll
    for (int i = 0; i < 4; ++i) {
      float r = sigmoidf_(a0[i] + br);
      float z = sigmoidf_(a1[i] + bz);
      float n = tanhf_((a3[i] + bi) + r*(a2[i] + bh));
      float hpf = (float)__builtin_bit_cast(f16, (unsigned short)hp[i]);
      stC2(hout + (size_t)(rowb+i)*H_ + j, (1.f - z)*n + z*hpf);
    }
    gbar(flags, go, bid, s+1);
  }

  // ---- decoder: restage gate ntiles; y-ntile in regs ----
  for (int it = 0; it < 16; ++it) {
    int idx = it*256 + tid;
    int nt = idx >> 10, r = idx & 1023;
    *(f16x8*)((char*)lds + (size_t)idx*16) =
        *(const f16x8*)((const char*)Wd + (size_t)(g*5+nt)*16384 + (size_t)r*16);
  }
  f16x8 yb[16];
  #pragma unroll
  for (int ks = 0; ks < 16; ++ks)
    yb[ks] = *(const f16x8*)((const char*)Wd + (size_t)(g*5+4)*16384
                             + (size_t)ks*1024 + (size_t)lane*16);
  float dr = bd[(g*5+0)*16+c], dz = bd[(g*5+1)*16+c];
  float dh = bd[(g*5+2)*16+c], di = bd[(g*5+3)*16+c], dy = bd[(g*5+4)*16+c];
  __syncthreads();

  for (int d = 0; d < L_-1; ++d, ++s) {
    const f16* hin  = (d & 1) ? h1 : h0;
    f16*       hout = (d & 1) ? h0 : h1;
    f16x8 ha[16];
    #pragma unroll
    for (int ks = 0; ks < 16; ++ks)
      ha[ks] = ldC(hin + (size_t)row0*H_ + ks*32 + (rq<<3));
    unsigned hp[4];
    #pragma unroll
    for (int i = 0; i < 4; ++i)
      hp[i] = ldC2(hin + (size_t)(rowb+i)*H_ + j);
    vwait0();
    f32x4 a0={},a1={},a2={},a3={},a4={};
    #pragma unroll
    for (int ks = 0; ks < 16; ++ks) {
      a0 = MFMA16(ha[ks], *(const f16x8*)(lds + (0*16+ks)*512 + lane*8), a0);
      a1 = MFMA16(ha[ks], *(const f16x8*)(lds + (1*16+ks)*512 + lane*8), a1);
      a2 = MFMA16(ha[ks], *(const f16x8*)(lds + (2*16+ks)*512 + lane*8), a2);
      a3 = MFMA16(ha[ks], *(const f16x8*)(lds + (3*16+ks)*512 + lane*8), a3);
      a4 = MFMA16(ha[ks], yb[ks], a4);
    }
    float* yo = out + (size_t)d*O_;
    #pragma unroll
    for (int i = 0; i < 4; ++i) {
      float r = sigmoidf_(a0[i] + dr);
      float z = sigmoidf_(a1[i] + dz);
      float n = tanhf_((a3[i] + di) + r*(a2[i] + dh));
      float hpf = (float)__builtin_bit_cast(f16, (unsigned short)hp[i]);
      stC2(hout + (size_t)(rowb+i)*H_ + j, (1.f - z)*n + z*hpf);
      if (c < 2) yo[(size_t)(rowb+i)*OUTSTR + 2*g + c] = a4[i] + dy;
    }
    gbar(flags, go, bid, s+1);
  }

  // ---- final y projection from h1 (written at d=298) ----
  {
    f16x8 ha[16];
    #pragma unroll
    for (int ks = 0; ks < 16; ++ks)
      ha[ks] = ldC(h1 + (size_t)row0*H_ + ks*32 + (rq<<3));
    vwait0();
    f32x4 a4 = {};
    #pragma unroll
    for (int ks = 0; ks < 16; ++ks) a4 = MFMA16(ha[ks], yb[ks], a4);
    if (c < 2) {
      #pragma unroll
      for (int i = 0; i < 4; ++i)
        out[(size_t)(rowb+i)*OUTSTR + (size_t)(L_-1)*O_ + 2*g + c] = a4[i] + dy;
    }
  }
}

// ---------------------------------------------------------------------------

extern "C" void kernel_launch(void* const* d_in, const int* in_sizes, int n_in,
                              void* d_out, int out_size, void* d_ws, size_t ws_size,
                              hipStream_t stream) {
  (void)in_sizes; (void)n_in; (void)out_size; (void)ws_size;
  const float* x   = (const float*)d_in[0];
  const float* Wih = (const float*)d_in[1];
  const float* Whh = (const float*)d_in[2];
  const float* bih = (const float*)d_in[3];
  const float* bhh = (const float*)d_in[4];
  const float* Wo  = (const float*)d_in[5];
  const float* bo  = (const float*)d_in[6];
  float* out = (float*)d_out;

  char* ws = (char*)d_ws;
  size_t off = 0;
  auto alloc = [&](size_t bytes) {
    char* p = ws + off;
    off += (bytes + 255) & ~(size_t)255;
    return p;
  };
  f16*   x16 = (f16*)  alloc((size_t)T_*B_*I_*2);
  f16*   hA  = (f16*)  alloc((size_t)B_*H_*2);
  f16*   hB  = (f16*)  alloc((size_t)B_*H_*2);
  f16*   We  = (f16*)  alloc((size_t)128*18*512*2);
  f16*   Wd  = (f16*)  alloc((size_t)160*16*512*2);
  float* Wf  = (float*)alloc((size_t)1536*512*4);
  float* be  = (float*)alloc(2048*4);
  float* bd  = (float*)alloc(2560*4);
  float* bf  = (float*)alloc(1536*4);
  unsigned* flags = (unsigned*)alloc(256*64);   // 64B-padded per-block flags
  unsigned* go    = (unsigned*)alloc(8*64);     // 8 replicated go lines

  hipMemsetAsync(flags, 0, 256*64 + 8*64, stream);
  hipLaunchKernelGGL(k_zero_h,   dim3((B_*H_+255)/256),    dim3(256), 0, stream, hA);
  hipLaunchKernelGGL(k_cvt_x,    dim3((T_*B_*I_+255)/256), dim3(256), 0, stream, x, x16);
  hipLaunchKernelGGL(k_fuse,     dim3(1536*512/256),       dim3(256), 0, stream, Wo, Wih, Wf);
  hipLaunchKernelGGL(k_bf,       dim3(6),                  dim3(256), 0, stream, bo, Wih, bf);
  hipLaunchKernelGGL(k_pack_enc, dim3(128*18*512/256),     dim3(256), 0, stream, Whh, Wih, We);
  hipLaunchKernelGGL(k_pack_dec, dim3(160*16*512/256),     dim3(256), 0, stream, Whh, Wo, Wf, Wd);
  hipLaunchKernelGGL(k_bias_enc, dim3(8),                  dim3(256), 0, stream, bih, bhh, be);
  hipLaunchKernelGGL(k_bias_dec, dim3(10),                 dim3(256), 0, stream, bih, bhh, bo, bf, bd);

  hipLaunchKernelGGL(k_persist, dim3(NBLK), dim3(256), 0, stream,
                     x16, We, Wd, be, bd, hA, hB, out, flags, go);
}

// Round 7
// 2765.876 us; speedup vs baseline: 4.5592x; 1.0292x over previous
//
#include <hip/hip_runtime.h>

typedef _Float16 f16;
typedef _Float16 f16x8 __attribute__((ext_vector_type(8)));
typedef float f32x4 __attribute__((ext_vector_type(4)));

#define B_ 512
#define T_ 128
#define I_ 64
#define H_ 512
#define O_ 64
#define L_ 300
#define OUTSTR (L_*O_)
#define NBLK 256

// ---------------------------------------------------------------------------
// Prologue kernels (verified R0/R1/R3). Packed B layout (MFMA 16x16x32 f16):
//   flat = ((ntile_global*KSTEPS + kstep)*64 + lane)*8 + elem
//   value = W[k][col], k = kstep*32 + (lane>>4)*8 + elem, col = lane&15
// ---------------------------------------------------------------------------

__global__ void k_zero_h(f16* h) {
  int i = blockIdx.x*256 + threadIdx.x;
  if (i < B_*H_) h[i] = (f16)0.f;
}

__global__ void k_cvt_x(const float* __restrict__ x, f16* __restrict__ x16) {
  int p = blockIdx.x*256 + threadIdx.x;
  if (p >= T_*B_*I_) return;
  int i = p & 63, b = (p >> 6) & 511, t = p >> 15;
  x16[p] = (f16)x[((size_t)b*T_ + t)*I_ + i];
}

__global__ void k_fuse(const float* __restrict__ Wo, const float* __restrict__ Wih,
                       float* __restrict__ Wf) {
  int p = blockIdx.x*256 + threadIdx.x;
  if (p >= 1536*512) return;
  int k = p & 511, j3 = p >> 9;
  float s = 0.f;
  for (int o = 0; o < 64; ++o) s += Wo[(size_t)o*H_ + k] * Wih[(size_t)j3*I_ + o];
  Wf[p] = s;
}

__global__ void k_bf(const float* __restrict__ bo, const float* __restrict__ Wih,
                     float* __restrict__ bf) {
  int j3 = blockIdx.x*256 + threadIdx.x;
  if (j3 >= 1536) return;
  float s = 0.f;
  for (int o = 0; o < 64; ++o) s += bo[o]*Wih[(size_t)j3*I_ + o];
  bf[j3] = s;
}

__global__ void k_pack_enc(const float* __restrict__ Whh, const float* __restrict__ Wih,
                           f16* __restrict__ We) {
  int p = blockIdx.x*256 + threadIdx.x;
  if (p >= 128*18*512) return;
  int i = p & 7, l = (p >> 3) & 63, ks = (p >> 9) % 18, ntg = p / (18*512);
  int g = ntg >> 2, nti = ntg & 3, c = l & 15;
  int j = g*16 + c, k = ks*32 + ((l>>4)<<3) + i;
  float v = 0.f;
  if (nti == 0)      v = (k < 512) ? Whh[(size_t)j*H_ + k]        : Wih[(size_t)j*I_ + (k-512)];
  else if (nti == 1) v = (k < 512) ? Whh[(size_t)(512+j)*H_ + k]  : Wih[(size_t)(512+j)*I_ + (k-512)];
  else if (nti == 2) v = (k < 512) ? Whh[(size_t)(1024+j)*H_ + k] : 0.f;
  else               v = (k >= 512)? Wih[(size_t)(1024+j)*I_ + (k-512)] : 0.f;
  We[p] = (f16)v;
}

__global__ void k_pack_dec(const float* __restrict__ Whh, const float* __restrict__ Wo,
                           const float* __restrict__ Wf, f16* __restrict__ Wd) {
  int p = blockIdx.x*256 + threadIdx.x;
  if (p >= 160*16*512) return;
  int i = p & 7, l = (p >> 3) & 63, ks = (p >> 9) & 15, ntg = p >> 13;
  int g = ntg/5, nti = ntg%5, c = l & 15;
  int j = g*16 + c, k = ks*32 + ((l>>4)<<3) + i;
  float v;
  if (nti == 0)      v = Whh[(size_t)j*H_+k]       + Wf[(size_t)j*512 + k];
  else if (nti == 1) v = Whh[(size_t)(512+j)*H_+k] + Wf[(size_t)(512+j)*512 + k];
  else if (nti == 2) v = Whh[(size_t)(1024+j)*H_+k];
  else if (nti == 3) v = Wf[(size_t)(1024+j)*512 + k];
  else               v = (c < 2) ? Wo[(size_t)(2*g+c)*H_ + k] : 0.f;
  Wd[p] = (f16)v;
}

__global__ void k_bias_enc(const float* __restrict__ bih, const float* __restrict__ bhh,
                           float* __restrict__ be) {
  int p = blockIdx.x*256 + threadIdx.x;
  if (p >= 2048) return;
  int c = p & 15, ntg = p >> 4, g = ntg >> 2, nti = ntg & 3, j = g*16 + c;
  float v;
  if (nti == 0)      v = bih[j] + bhh[j];
  else if (nti == 1) v = bih[512+j] + bhh[512+j];
  else if (nti == 2) v = bhh[1024+j];
  else               v = bih[1024+j];
  be[p] = v;
}

__global__ void k_bias_dec(const float* __restrict__ bih, const float* __restrict__ bhh,
                           const float* __restrict__ bo, const float* __restrict__ bf,
                           float* __restrict__ bd) {
  int p = blockIdx.x*256 + threadIdx.x;
  if (p >= 2560) return;
  int c = p & 15, ntg = p >> 4, g = ntg/5, nti = ntg%5, j = g*16 + c;
  float v;
  if (nti == 0)      v = bih[j] + bhh[j] + bf[j];
  else if (nti == 1) v = bih[512+j] + bhh[512+j] + bf[512+j];
  else if (nti == 2) v = bhh[1024+j];
  else if (nti == 3) v = bih[1024+j] + bf[1024+j];
  else               v = (c < 2) ? bo[2*g+c] : 0.f;
  bd[p] = v;
}

// ---------------------------------------------------------------------------
// R6 = R3's proven compute core (single vmcnt(0) drain, no counted waits, no
// x-prefetch) + two audited deltas: (1) slab-scoped two-round leader barrier
// in R3's exact atomic style; (2) hprev carried in registers.
// Coherence (R3-proven): h stores/loads sc0 sc1 (LLC coherence point, no
// fences, no wbl2/inv, any block->XCD map).
// ---------------------------------------------------------------------------

__device__ __forceinline__ float sigmoidf_(float x){ return 1.f/(1.f + __expf(-x)); }
__device__ __forceinline__ float tanhf_(float x){ return 1.f - 2.f/(__expf(2.f*x) + 1.f); }

__device__ __forceinline__ f16x8 ldC(const f16* p) {     // coherent 16B load
  f16x8 r;
  asm volatile("global_load_dwordx4 %0, %1, off sc0 sc1" : "=&v"(r) : "v"(p));
  return r;
}
__device__ __forceinline__ f16x8 ldP(const f16* p) {     // read-only (x16), cached
  f16x8 r;
  asm volatile("global_load_dwordx4 %0, %1, off" : "=&v"(r) : "v"(p));
  return r;
}
__device__ __forceinline__ void stC2(f16* p, f16 h) {    // coherent 2B store
  unsigned b = (unsigned)__builtin_bit_cast(unsigned short, h);
  asm volatile("global_store_short %0, %1, off sc0 sc1" :: "v"(p), "v"(b) : "memory");
}
// Single full drain before MFMA consumption (R3-proven).
__device__ __forceinline__ void vwait0() {
  asm volatile("s_waitcnt vmcnt(0)" ::: "memory");
  __builtin_amdgcn_sched_barrier(0);
}

// Slab-scoped two-round barrier (R3 gbar2 mechanics, group = 32 blocks of one
// slab). Leader = the slab's g==0 block: polls the slab's 32 padded flags,
// then raises the slab's go line. Compiler-generated RELAXED/AGENT atomics.
__device__ __forceinline__ void sbar(unsigned* __restrict__ flags,
                                     unsigned* __restrict__ go,
                                     int bm, int g, unsigned tgt) {
  asm volatile("s_waitcnt vmcnt(0)" ::: "memory");  // asm h-stores LLC-visible
  __syncthreads();                                  // all 4 waves drained
  const int tid = threadIdx.x;
  if (g == 0) {
    if (tid < 64) {
      if (tid == 0)
        __hip_atomic_store(&flags[(bm*32)*16], tgt, __ATOMIC_RELAXED,
                           __HIP_MEMORY_SCOPE_AGENT);
      unsigned v;
      do {
        v = __hip_atomic_load(&flags[(bm*32 + (tid & 31))*16], __ATOMIC_RELAXED,
                              __HIP_MEMORY_SCOPE_AGENT);
      } while (!__all(v >= tgt));
      if (tid == 0)
        __hip_atomic_store(&go[bm*16], tgt, __ATOMIC_RELAXED,
                           __HIP_MEMORY_SCOPE_AGENT);
    }
  } else {
    if (tid == 0) {
      __hip_atomic_store(&flags[(bm*32 + g)*16], tgt, __ATOMIC_RELAXED,
                         __HIP_MEMORY_SCOPE_AGENT);
      while (__hip_atomic_load(&go[bm*16], __ATOMIC_RELAXED,
                               __HIP_MEMORY_SCOPE_AGENT) < tgt)
        __builtin_amdgcn_s_sleep(2);
    }
  }
  __syncthreads();
  __builtin_amdgcn_sched_barrier(0);
}

#define MFMA16(a,b,acc) __builtin_amdgcn_mfma_f32_16x16x32_f16(a, b, acc, 0, 0, 0)

__global__ __launch_bounds__(256, 1) void k_persist(
    const f16* __restrict__ x16, const f16* __restrict__ We,
    const f16* __restrict__ Wd, const float* __restrict__ be,
    const float* __restrict__ bd, f16* __restrict__ h0, f16* __restrict__ h1,
    float* __restrict__ out, unsigned* __restrict__ flags,
    unsigned* __restrict__ go) {
  __shared__ f16 lds[32768];               // 64 KiB: 4 ntiles x 16 ksteps x 1KB
  const int tid = threadIdx.x, bid = blockIdx.x, w = tid >> 6, lane = tid & 63;
  const int g = bid & 31, bm = bid >> 5;   // col-group, row-slab
  const int c = lane & 15, rq = lane >> 4;
  const int row0 = bm*64 + w*16 + c;       // A-fragment row
  const int rowb = bm*64 + w*16 + rq*4;    // C/D row base
  const int j = g*16 + c;

  // ---- encoder: stage K=512 h-part weights to LDS once; x-part in regs ----
  for (int it = 0; it < 16; ++it) {
    int idx = it*256 + tid;
    int nt = idx >> 10, r = idx & 1023;
    *(f16x8*)((char*)lds + (size_t)idx*16) =
        *(const f16x8*)((const char*)We + (size_t)(g*4+nt)*18432 + (size_t)r*16);
  }
  f16x8 bx0,bx1,bx2,bx3,bx4,bx5,bx6,bx7;
  {
    const char* base = (const char*)We + (size_t)lane*16 + 16*1024;
    bx0 = *(const f16x8*)(base + (size_t)(g*4+0)*18432);
    bx1 = *(const f16x8*)(base + (size_t)(g*4+1)*18432);
    bx2 = *(const f16x8*)(base + (size_t)(g*4+2)*18432);
    bx3 = *(const f16x8*)(base + (size_t)(g*4+3)*18432);
    bx4 = *(const f16x8*)(base + (size_t)(g*4+0)*18432 + 1024);
    bx5 = *(const f16x8*)(base + (size_t)(g*4+1)*18432 + 1024);
    bx6 = *(const f16x8*)(base + (size_t)(g*4+2)*18432 + 1024);
    bx7 = *(const f16x8*)(base + (size_t)(g*4+3)*18432 + 1024);
  }
  float br = be[(g*4+0)*16+c], bz = be[(g*4+1)*16+c];
  float bh = be[(g*4+2)*16+c], bi = be[(g*4+3)*16+c];
  float hprev[4] = {0.f, 0.f, 0.f, 0.f};   // h_in[rowb+i][j], owned by THIS
                                           // thread (h0 starts zeroed)
  __syncthreads();

  unsigned s = 0;   // global step index 0..426
  for (int t = 0; t < T_; ++t, ++s) {
    const f16* hin  = (t & 1) ? h1 : h0;
    f16*       hout = (t & 1) ? h0 : h1;
    const f16* xt = x16 + (size_t)t*B_*I_;
    f16x8 ha[16];
    #pragma unroll
    for (int ks = 0; ks < 16; ++ks)
      ha[ks] = ldC(hin + (size_t)row0*H_ + ks*32 + (rq<<3));
    f16x8 ax = ldP(xt + (size_t)row0*I_ + (rq<<3));
    f16x8 ay = ldP(xt + (size_t)row0*I_ + 32 + (rq<<3));
    vwait0();
    f32x4 a0={},a1={},a2={},a3={};
    #pragma unroll
    for (int ks = 0; ks < 16; ++ks) {
      a0 = MFMA16(ha[ks], *(const f16x8*)(lds + (0*16+ks)*512 + lane*8), a0);
      a1 = MFMA16(ha[ks], *(const f16x8*)(lds + (1*16+ks)*512 + lane*8), a1);
      a2 = MFMA16(ha[ks], *(const f16x8*)(lds + (2*16+ks)*512 + lane*8), a2);
      a3 = MFMA16(ha[ks], *(const f16x8*)(lds + (3*16+ks)*512 + lane*8), a3);
    }
    a0 = MFMA16(ax, bx0, a0); a1 = MFMA16(ax, bx1, a1);
    a2 = MFMA16(ax, bx2, a2); a3 = MFMA16(ax, bx3, a3);
    a0 = MFMA16(ay, bx4, a0); a1 = MFMA16(ay, bx5, a1);
    a2 = MFMA16(ay, bx6, a2); a3 = MFMA16(ay, bx7, a3);
    #pragma unroll
    for (int i = 0; i < 4; ++i) {
      float r = sigmoidf_(a0[i] + br);
      float z = sigmoidf_(a1[i] + bz);
      float n = tanhf_((a3[i] + bi) + r*(a2[i] + bh));
      f16 hv = (f16)((1.f - z)*n + z*hprev[i]);
      stC2(hout + (size_t)(rowb+i)*H_ + j, hv);
      hprev[i] = (float)hv;
    }
    sbar(flags, go, bm, g, s+1);
  }

  // ---- decoder: restage gate ntiles; y-ntile in regs ----
  __syncthreads();
  for (int it = 0; it < 16; ++it) {
    int idx = it*256 + tid;
    int nt = idx >> 10, r = idx & 1023;
    *(f16x8*)((char*)lds + (size_t)idx*16) =
        *(const f16x8*)((const char*)Wd + (size_t)(g*5+nt)*16384 + (size_t)r*16);
  }
  f16x8 yb[16];
  #pragma unroll
  for (int ks = 0; ks < 16; ++ks)
    yb[ks] = *(const f16x8*)((const char*)Wd + (size_t)(g*5+4)*16384
                             + (size_t)ks*1024 + (size_t)lane*16);
  float dr = bd[(g*5+0)*16+c], dz = bd[(g*5+1)*16+c];
  float dh = bd[(g*5+2)*16+c], di = bd[(g*5+3)*16+c], dy = bd[(g*5+4)*16+c];
  __syncthreads();

  for (int d = 0; d < L_-1; ++d, ++s) {
    const f16* hin  = (d & 1) ? h1 : h0;
    f16*       hout = (d & 1) ? h0 : h1;
    f16x8 ha[16];
    #pragma unroll
    for (int ks = 0; ks < 16; ++ks)
      ha[ks] = ldC(hin + (size_t)row0*H_ + ks*32 + (rq<<3));
    vwait0();
    f32x4 a0={},a1={},a2={},a3={},a4={};
    #pragma unroll
    for (int ks = 0; ks < 16; ++ks) {
      a0 = MFMA16(ha[ks], *(const f16x8*)(lds + (0*16+ks)*512 + lane*8), a0);
      a1 = MFMA16(ha[ks], *(const f16x8*)(lds + (1*16+ks)*512 + lane*8), a1);
      a2 = MFMA16(ha[ks], *(const f16x8*)(lds + (2*16+ks)*512 + lane*8), a2);
      a3 = MFMA16(ha[ks], *(const f16x8*)(lds + (3*16+ks)*512 + lane*8), a3);
      a4 = MFMA16(ha[ks], yb[ks], a4);
    }
    float* yo = out + (size_t)d*O_;
    #pragma unroll
    for (int i = 0; i < 4; ++i) {
      float r = sigmoidf_(a0[i] + dr);
      float z = sigmoidf_(a1[i] + dz);
      float n = tanhf_((a3[i] + di) + r*(a2[i] + dh));
      f16 hv = (f16)((1.f - z)*n + z*hprev[i]);
      stC2(hout + (size_t)(rowb+i)*H_ + j, hv);
      hprev[i] = (float)hv;
      if (c < 2) yo[(size_t)(rowb+i)*OUTSTR + 2*g + c] = a4[i] + dy;
    }
    sbar(flags, go, bm, g, s+1);
  }

  // ---- final y projection from h1 (written at d=298; slab-local) ----
  {
    f16x8 ha[16];
    #pragma unroll
    for (int ks = 0; ks < 16; ++ks)
      ha[ks] = ldC(h1 + (size_t)row0*H_ + ks*32 + (rq<<3));
    vwait0();
    f32x4 a4 = {};
    #pragma unroll
    for (int ks = 0; ks < 16; ++ks) a4 = MFMA16(ha[ks], yb[ks], a4);
    if (c < 2) {
      #pragma unroll
      for (int i = 0; i < 4; ++i)
        out[(size_t)(rowb+i)*OUTSTR + (size_t)(L_-1)*O_ + 2*g + c] = a4[i] + dy;
    }
  }
}

// ---------------------------------------------------------------------------

extern "C" void kernel_launch(void* const* d_in, const int* in_sizes, int n_in,
                              void* d_out, int out_size, void* d_ws, size_t ws_size,
                              hipStream_t stream) {
  (void)in_sizes; (void)n_in; (void)out_size; (void)ws_size;
  const float* x   = (const float*)d_in[0];
  const float* Wih = (const float*)d_in[1];
  const float* Whh = (const float*)d_in[2];
  const float* bih = (const float*)d_in[3];
  const float* bhh = (const float*)d_in[4];
  const float* Wo  = (const float*)d_in[5];
  const float* bo  = (const float*)d_in[6];
  float* out = (float*)d_out;

  char* ws = (char*)d_ws;
  size_t off = 0;
  auto alloc = [&](size_t bytes) {
    char* p = ws + off;
    off += (bytes + 255) & ~(size_t)255;
    return p;
  };
  f16*   x16 = (f16*)  alloc((size_t)T_*B_*I_*2);
  f16*   hA  = (f16*)  alloc((size_t)B_*H_*2);
  f16*   hB  = (f16*)  alloc((size_t)B_*H_*2);
  f16*   We  = (f16*)  alloc((size_t)128*18*512*2);
  f16*   Wd  = (f16*)  alloc((size_t)160*16*512*2);
  float* Wf  = (float*)alloc((size_t)1536*512*4);
  float* be  = (float*)alloc(2048*4);
  float* bd  = (float*)alloc(2560*4);
  float* bf  = (float*)alloc(1536*4);
  unsigned* flags = (unsigned*)alloc(256*64);   // 64B-padded flags (8 slabs x 32)
  unsigned* go    = (unsigned*)alloc(8*64);     // one 64B go line per slab

  hipMemsetAsync(flags, 0, 256*64 + 8*64, stream);
  hipLaunchKernelGGL(k_zero_h,   dim3((B_*H_+255)/256),    dim3(256), 0, stream, hA);
  hipLaunchKernelGGL(k_cvt_x,    dim3((T_*B_*I_+255)/256), dim3(256), 0, stream, x, x16);
  hipLaunchKernelGGL(k_fuse,     dim3(1536*512/256),       dim3(256), 0, stream, Wo, Wih, Wf);
  hipLaunchKernelGGL(k_bf,       dim3(6),                  dim3(256), 0, stream, bo, Wih, bf);
  hipLaunchKernelGGL(k_pack_enc, dim3(128*18*512/256),     dim3(256), 0, stream, Whh, Wih, We);
  hipLaunchKernelGGL(k_pack_dec, dim3(160*16*512/256),     dim3(256), 0, stream, Whh, Wo, Wf, Wd);
  hipLaunchKernelGGL(k_bias_enc, dim3(8),                  dim3(256), 0, stream, bih, bhh, be);
  hipLaunchKernelGGL(k_bias_dec, dim3(10),                 dim3(256), 0, stream, bih, bhh, bo, bf, bd);

  hipLaunchKernelGGL(k_persist, dim3(NBLK), dim3(256), 0, stream,
                     x16, We, Wd, be, bd, hA, hB, out, flags, go);
}

// Round 9
// 2228.217 us; speedup vs baseline: 5.6593x; 1.2413x over previous
//
#include <hip/hip_runtime.h>

typedef _Float16 f16;
typedef _Float16 f16x8 __attribute__((ext_vector_type(8)));
typedef float f32x4 __attribute__((ext_vector_type(4)));

#define B_ 512
#define T_ 128
#define I_ 64
#define H_ 512
#define O_ 64
#define L_ 300
#define OUTSTR (L_*O_)
#define NBLK 256

// ---------------------------------------------------------------------------
// Prologue kernels (verified R0/R1/R3). Packed B layout (MFMA 16x16x32 f16):
//   flat = ((ntile_global*KSTEPS + kstep)*64 + lane)*8 + elem
//   value = W[k][col], k = kstep*32 + (lane>>4)*8 + elem, col = lane&15
// ---------------------------------------------------------------------------

__global__ void k_zero_h(f16* h) {
  int i = blockIdx.x*256 + threadIdx.x;
  if (i < B_*H_) h[i] = (f16)0.f;
}

__global__ void k_cvt_x(const float* __restrict__ x, f16* __restrict__ x16) {
  int p = blockIdx.x*256 + threadIdx.x;
  if (p >= T_*B_*I_) return;
  int i = p & 63, b = (p >> 6) & 511, t = p >> 15;
  x16[p] = (f16)x[((size_t)b*T_ + t)*I_ + i];
}

__global__ void k_fuse(const float* __restrict__ Wo, const float* __restrict__ Wih,
                       float* __restrict__ Wf) {
  int p = blockIdx.x*256 + threadIdx.x;
  if (p >= 1536*512) return;
  int k = p & 511, j3 = p >> 9;
  float s = 0.f;
  for (int o = 0; o < 64; ++o) s += Wo[(size_t)o*H_ + k] * Wih[(size_t)j3*I_ + o];
  Wf[p] = s;
}

__global__ void k_bf(const float* __restrict__ bo, const float* __restrict__ Wih,
                     float* __restrict__ bf) {
  int j3 = blockIdx.x*256 + threadIdx.x;
  if (j3 >= 1536) return;
  float s = 0.f;
  for (int o = 0; o < 64; ++o) s += bo[o]*Wih[(size_t)j3*I_ + o];
  bf[j3] = s;
}

__global__ void k_pack_enc(const float* __restrict__ Whh, const float* __restrict__ Wih,
                           f16* __restrict__ We) {
  int p = blockIdx.x*256 + threadIdx.x;
  if (p >= 128*18*512) return;
  int i = p & 7, l = (p >> 3) & 63, ks = (p >> 9) % 18, ntg = p / (18*512);
  int g = ntg >> 2, nti = ntg & 3, c = l & 15;
  int j = g*16 + c, k = ks*32 + ((l>>4)<<3) + i;
  float v = 0.f;
  if (nti == 0)      v = (k < 512) ? Whh[(size_t)j*H_ + k]        : Wih[(size_t)j*I_ + (k-512)];
  else if (nti == 1) v = (k < 512) ? Whh[(size_t)(512+j)*H_ + k]  : Wih[(size_t)(512+j)*I_ + (k-512)];
  else if (nti == 2) v = (k < 512) ? Whh[(size_t)(1024+j)*H_ + k] : 0.f;
  else               v = (k >= 512)? Wih[(size_t)(1024+j)*I_ + (k-512)] : 0.f;
  We[p] = (f16)v;
}

__global__ void k_pack_dec(const float* __restrict__ Whh, const float* __restrict__ Wo,
                           const float* __restrict__ Wf, f16* __restrict__ Wd) {
  int p = blockIdx.x*256 + threadIdx.x;
  if (p >= 160*16*512) return;
  int i = p & 7, l = (p >> 3) & 63, ks = (p >> 9) & 15, ntg = p >> 13;
  int g = ntg/5, nti = ntg%5, c = l & 15;
  int j = g*16 + c, k = ks*32 + ((l>>4)<<3) + i;
  float v;
  if (nti == 0)      v = Whh[(size_t)j*H_+k]       + Wf[(size_t)j*512 + k];
  else if (nti == 1) v = Whh[(size_t)(512+j)*H_+k] + Wf[(size_t)(512+j)*512 + k];
  else if (nti == 2) v = Whh[(size_t)(1024+j)*H_+k];
  else if (nti == 3) v = Wf[(size_t)(1024+j)*512 + k];
  else               v = (c < 2) ? Wo[(size_t)(2*g+c)*H_ + k] : 0.f;
  Wd[p] = (f16)v;
}

__global__ void k_bias_enc(const float* __restrict__ bih, const float* __restrict__ bhh,
                           float* __restrict__ be) {
  int p = blockIdx.x*256 + threadIdx.x;
  if (p >= 2048) return;
  int c = p & 15, ntg = p >> 4, g = ntg >> 2, nti = ntg & 3, j = g*16 + c;
  float v;
  if (nti == 0)      v = bih[j] + bhh[j];
  else if (nti == 1) v = bih[512+j] + bhh[512+j];
  else if (nti == 2) v = bhh[1024+j];
  else               v = bih[1024+j];
  be[p] = v;
}

__global__ void k_bias_dec(const float* __restrict__ bih, const float* __restrict__ bhh,
                           const float* __restrict__ bo, const float* __restrict__ bf,
                           float* __restrict__ bd) {
  int p = blockIdx.x*256 + threadIdx.x;
  if (p >= 2560) return;
  int c = p & 15, ntg = p >> 4, g = ntg/5, nti = ntg%5, j = g*16 + c;
  float v;
  if (nti == 0)      v = bih[j] + bhh[j] + bf[j];
  else if (nti == 1) v = bih[512+j] + bhh[512+j] + bf[512+j];
  else if (nti == 2) v = bhh[1024+j];
  else if (nti == 3) v = bih[1024+j] + bf[1024+j];
  else               v = (c < 2) ? bo[2*g+c] : 0.f;
  bd[p] = v;
}

// ---------------------------------------------------------------------------
// R8: XCD-local h DATA path (sc0 write-through stores + sc0 L2 loads), with
// the R6-PROVEN per-slab LLC barrier kept in BOTH paths (no new spin loops in
// the main loop -> a wrong sc0 assumption can only FAIL, never hang).
// Verified mapping: blocks publish XCC_ID|8; block 0 decides; all poll the
// verdict (acyclic waits -> deadlock-free). Fallback = R6 sc0 sc1 verbatim.
// R2/R7 lesson: PLAIN stores never publish (retire into write-back L1).
// ---------------------------------------------------------------------------

__device__ __forceinline__ float sigmoidf_(float x){ return 1.f/(1.f + __expf(-x)); }
__device__ __forceinline__ float tanhf_(float x){ return 1.f - 2.f/(__expf(2.f*x) + 1.f); }

template<bool FA>
__device__ __forceinline__ f16x8 ldA(const f16* p) {     // coherent 16B load
  f16x8 r;
  if (FA) asm volatile("global_load_dwordx4 %0, %1, off sc0"     : "=&v"(r) : "v"(p));
  else    asm volatile("global_load_dwordx4 %0, %1, off sc0 sc1" : "=&v"(r) : "v"(p));
  return r;
}
__device__ __forceinline__ f16x8 ldP(const f16* p) {     // read-only (x16), cached
  f16x8 r;
  asm volatile("global_load_dwordx4 %0, %1, off" : "=&v"(r) : "v"(p));
  return r;
}
template<bool FA>
__device__ __forceinline__ void stH(f16* p, f16 h) {     // write-through 2B store
  unsigned b = (unsigned)__builtin_bit_cast(unsigned short, h);
  if (FA) asm volatile("global_store_short %0, %1, off sc0"     :: "v"(p), "v"(b) : "memory");
  else    asm volatile("global_store_short %0, %1, off sc0 sc1" :: "v"(p), "v"(b) : "memory");
}
// Single full drain before MFMA consumption (R3/R6-proven).
__device__ __forceinline__ void vwait0() {
  asm volatile("s_waitcnt vmcnt(0)" ::: "memory");
  __builtin_amdgcn_sched_barrier(0);
}

// Per-slab two-round leader barrier, LLC, compiler atomics (R6-proven).
__device__ __forceinline__ void sbar(unsigned* __restrict__ flags,
                                     unsigned* __restrict__ go,
                                     int bm, int g, unsigned tgt) {
  asm volatile("s_waitcnt vmcnt(0)" ::: "memory");  // h stores visible first
  __syncthreads();                                  // all 4 waves drained
  const int tid = threadIdx.x;
  if (g == 0) {
    if (tid < 64) {
      if (tid == 0)
        __hip_atomic_store(&flags[(bm*32)*16], tgt, __ATOMIC_RELAXED,
                           __HIP_MEMORY_SCOPE_AGENT);
      unsigned v;
      do {
        v = __hip_atomic_load(&flags[(bm*32 + (tid & 31))*16], __ATOMIC_RELAXED,
                              __HIP_MEMORY_SCOPE_AGENT);
      } while (!__all(v >= tgt));
      if (tid == 0)
        __hip_atomic_store(&go[bm*16], tgt, __ATOMIC_RELAXED,
                           __HIP_MEMORY_SCOPE_AGENT);
    }
  } else {
    if (tid == 0) {
      __hip_atomic_store(&flags[(bm*32 + g)*16], tgt, __ATOMIC_RELAXED,
                         __HIP_MEMORY_SCOPE_AGENT);
      while (__hip_atomic_load(&go[bm*16], __ATOMIC_RELAXED,
                               __HIP_MEMORY_SCOPE_AGENT) < tgt)
        __builtin_amdgcn_s_sleep(2);
    }
  }
  __syncthreads();
  __builtin_amdgcn_sched_barrier(0);
}

#define MFMA16(a,b,acc) __builtin_amdgcn_mfma_f32_16x16x32_f16(a, b, acc, 0, 0, 0)

template<bool FA>
__device__ __forceinline__ void run_loop(
    const f16* __restrict__ x16, const f16* __restrict__ We,
    const f16* __restrict__ Wd, const float* __restrict__ be,
    const float* __restrict__ bd, f16* __restrict__ h0, f16* __restrict__ h1,
    float* __restrict__ out, unsigned* __restrict__ flags,
    unsigned* __restrict__ go, f16* lds, int bm, int g) {
  const int tid = threadIdx.x, w = tid >> 6, lane = tid & 63;
  const int c = lane & 15, rq = lane >> 4;
  const int row0 = bm*64 + w*16 + c;       // A-fragment row
  const int rowb = bm*64 + w*16 + rq*4;    // C/D row base
  const int j = g*16 + c;

  // ---- encoder: stage K=512 h-part weights to LDS once; x-part in regs ----
  for (int it = 0; it < 16; ++it) {
    int idx = it*256 + tid;
    int nt = idx >> 10, r = idx & 1023;
    *(f16x8*)((char*)lds + (size_t)idx*16) =
        *(const f16x8*)((const char*)We + (size_t)(g*4+nt)*18432 + (size_t)r*16);
  }
  f16x8 bx0,bx1,bx2,bx3,bx4,bx5,bx6,bx7;
  {
    const char* base = (const char*)We + (size_t)lane*16 + 16*1024;
    bx0 = *(const f16x8*)(base + (size_t)(g*4+0)*18432);
    bx1 = *(const f16x8*)(base + (size_t)(g*4+1)*18432);
    bx2 = *(const f16x8*)(base + (size_t)(g*4+2)*18432);
    bx3 = *(const f16x8*)(base + (size_t)(g*4+3)*18432);
    bx4 = *(const f16x8*)(base + (size_t)(g*4+0)*18432 + 1024);
    bx5 = *(const f16x8*)(base + (size_t)(g*4+1)*18432 + 1024);
    bx6 = *(const f16x8*)(base + (size_t)(g*4+2)*18432 + 1024);
    bx7 = *(const f16x8*)(base + (size_t)(g*4+3)*18432 + 1024);
  }
  float br = be[(g*4+0)*16+c], bz = be[(g*4+1)*16+c];
  float bh = be[(g*4+2)*16+c], bi = be[(g*4+3)*16+c];
  float hprev[4] = {0.f, 0.f, 0.f, 0.f};   // h_in[rowb+i][j], owned by THIS
                                           // thread (h0 starts zeroed)
  __syncthreads();

  unsigned s = 0;   // global step index 0..426
  for (int t = 0; t < T_; ++t, ++s) {
    const f16* hin  = (t & 1) ? h1 : h0;
    f16*       hout = (t & 1) ? h0 : h1;
    const f16* xt = x16 + (size_t)t*B_*I_;
    f16x8 ha[16];
    #pragma unroll
    for (int ks = 0; ks < 16; ++ks)
      ha[ks] = ldA<FA>(hin + (size_t)row0*H_ + ks*32 + (rq<<3));
    f16x8 ax = ldP(xt + (size_t)row0*I_ + (rq<<3));
    f16x8 ay = ldP(xt + (size_t)row0*I_ + 32 + (rq<<3));
    vwait0();
    f32x4 a0={},a1={},a2={},a3={};
    #pragma unroll
    for (int ks = 0; ks < 16; ++ks) {
      a0 = MFMA16(ha[ks], *(const f16x8*)(lds + (0*16+ks)*512 + lane*8), a0);
      a1 = MFMA16(ha[ks], *(const f16x8*)(lds + (1*16+ks)*512 + lane*8), a1);
      a2 = MFMA16(ha[ks], *(const f16x8*)(lds + (2*16+ks)*512 + lane*8), a2);
      a3 = MFMA16(ha[ks], *(const f16x8*)(lds + (3*16+ks)*512 + lane*8), a3);
    }
    a0 = MFMA16(ax, bx0, a0); a1 = MFMA16(ax, bx1, a1);
    a2 = MFMA16(ax, bx2, a2); a3 = MFMA16(ax, bx3, a3);
    a0 = MFMA16(ay, bx4, a0); a1 = MFMA16(ay, bx5, a1);
    a2 = MFMA16(ay, bx6, a2); a3 = MFMA16(ay, bx7, a3);
    #pragma unroll
    for (int i = 0; i < 4; ++i) {
      float r = sigmoidf_(a0[i] + br);
      float z = sigmoidf_(a1[i] + bz);
      float n = tanhf_((a3[i] + bi) + r*(a2[i] + bh));
      f16 hv = (f16)((1.f - z)*n + z*hprev[i]);
      stH<FA>(hout + (size_t)(rowb+i)*H_ + j, hv);
      hprev[i] = (float)hv;
    }
    sbar(flags, go, bm, g, s+1);
  }

  // ---- decoder: restage gate ntiles; y-ntile in regs ----
  __syncthreads();
  for (int it = 0; it < 16; ++it) {
    int idx = it*256 + tid;
    int nt = idx >> 10, r = idx & 1023;
    *(f16x8*)((char*)lds + (size_t)idx*16) =
        *(const f16x8*)((const char*)Wd + (size_t)(g*5+nt)*16384 + (size_t)r*16);
  }
  f16x8 yb[16];
  #pragma unroll
  for (int ks = 0; ks < 16; ++ks)
    yb[ks] = *(const f16x8*)((const char*)Wd + (size_t)(g*5+4)*16384
                             + (size_t)ks*1024 + (size_t)lane*16);
  float dr = bd[(g*5+0)*16+c], dz = bd[(g*5+1)*16+c];
  float dh = bd[(g*5+2)*16+c], di = bd[(g*5+3)*16+c], dy = bd[(g*5+4)*16+c];
  __syncthreads();

  for (int d = 0; d < L_-1; ++d, ++s) {
    const f16* hin  = (d & 1) ? h1 : h0;
    f16*       hout = (d & 1) ? h0 : h1;
    f16x8 ha[16];
    #pragma unroll
    for (int ks = 0; ks < 16; ++ks)
      ha[ks] = ldA<FA>(hin + (size_t)row0*H_ + ks*32 + (rq<<3));
    vwait0();
    f32x4 a0={},a1={},a2={},a3={},a4={};
    #pragma unroll
    for (int ks = 0; ks < 16; ++ks) {
      a0 = MFMA16(ha[ks], *(const f16x8*)(lds + (0*16+ks)*512 + lane*8), a0);
      a1 = MFMA16(ha[ks], *(const f16x8*)(lds + (1*16+ks)*512 + lane*8), a1);
      a2 = MFMA16(ha[ks], *(const f16x8*)(lds + (2*16+ks)*512 + lane*8), a2);
      a3 = MFMA16(ha[ks], *(const f16x8*)(lds + (3*16+ks)*512 + lane*8), a3);
      a4 = MFMA16(ha[ks], yb[ks], a4);
    }
    float* yo = out + (size_t)d*O_;
    #pragma unroll
    for (int i = 0; i < 4; ++i) {
      float r = sigmoidf_(a0[i] + dr);
      float z = sigmoidf_(a1[i] + dz);
      float n = tanhf_((a3[i] + di) + r*(a2[i] + dh));
      f16 hv = (f16)((1.f - z)*n + z*hprev[i]);
      stH<FA>(hout + (size_t)(rowb+i)*H_ + j, hv);
      hprev[i] = (float)hv;
      if (c < 2) yo[(size_t)(rowb+i)*OUTSTR + 2*g + c] = a4[i] + dy;
    }
    sbar(flags, go, bm, g, s+1);
  }

  // ---- final y projection from h1 (written at d=298; slab-local) ----
  {
    f16x8 ha[16];
    #pragma unroll
    for (int ks = 0; ks < 16; ++ks)
      ha[ks] = ldA<FA>(h1 + (size_t)row0*H_ + ks*32 + (rq<<3));
    vwait0();
    f32x4 a4 = {};
    #pragma unroll
    for (int ks = 0; ks < 16; ++ks) a4 = MFMA16(ha[ks], yb[ks], a4);
    if (c < 2) {
      #pragma unroll
      for (int i = 0; i < 4; ++i)
        out[(size_t)(rowb+i)*OUTSTR + (size_t)(L_-1)*O_ + 2*g + c] = a4[i] + dy;
    }
  }
}

__global__ __launch_bounds__(256, 1) void k_persist(
    const f16* __restrict__ x16, const f16* __restrict__ We,
    const f16* __restrict__ Wd, const float* __restrict__ be,
    const float* __restrict__ bd, f16* __restrict__ h0, f16* __restrict__ h1,
    float* __restrict__ out, unsigned* __restrict__ stepFlags,
    unsigned* __restrict__ stepGo, unsigned* __restrict__ xcds,
    unsigned* __restrict__ verdict) {
  __shared__ f16 lds[32768];
  const int tid = threadIdx.x, bid = blockIdx.x;

  // ---- every block unconditionally publishes XCC_ID|8 (nonzero marker) ----
  if (tid == 0) {
    unsigned xcc;
    asm volatile("s_getreg_b32 %0, hwreg(HW_REG_XCC_ID)" : "=s"(xcc));
    __hip_atomic_store(&xcds[bid], (xcc & 7u) | 8u, __ATOMIC_RELAXED,
                       __HIP_MEMORY_SCOPE_AGENT);
  }
  // ---- block 0: wait all published, decide, publish verdict (acyclic) ----
  if (bid == 0 && tid < 64) {
    for (;;) {
      int ready = 1;
      for (int k2 = 0; k2 < 4; ++k2)
        ready &= (__hip_atomic_load(&xcds[tid*4 + k2], __ATOMIC_RELAXED,
                                    __HIP_MEMORY_SCOPE_AGENT) >= 8u);
      if (__ballot(ready != 0) == ~0ull) break;
      __builtin_amdgcn_s_sleep(2);
    }
    int okA = 1, okB = 1;
    for (int k2 = 0; k2 < 4; ++k2) {
      int b2 = tid*4 + k2;
      unsigned xv = __hip_atomic_load(&xcds[b2],         __ATOMIC_RELAXED, __HIP_MEMORY_SCOPE_AGENT);
      unsigned ra = __hip_atomic_load(&xcds[b2 & 7],     __ATOMIC_RELAXED, __HIP_MEMORY_SCOPE_AGENT);
      unsigned rb = __hip_atomic_load(&xcds[(b2>>5)<<5], __ATOMIC_RELAXED, __HIP_MEMORY_SCOPE_AGENT);
      okA &= (xv == ra); okB &= (xv == rb);
    }
    bool allA = (__ballot(okA != 0) == ~0ull);
    bool allB = (__ballot(okB != 0) == ~0ull);
    if (tid == 0)
      __hip_atomic_store(verdict, allA ? 2u : (allB ? 3u : 1u),
                         __ATOMIC_RELAXED, __HIP_MEMORY_SCOPE_AGENT);
  }
  // ---- all blocks poll the single verdict (block 0 only waits on xcds,
  //      which are published unconditionally -> no circular dependency) ----
  volatile unsigned* shm = (volatile unsigned*)lds;
  if (tid == 0) {
    unsigned vv;
    for (;;) {
      vv = __hip_atomic_load(verdict, __ATOMIC_RELAXED, __HIP_MEMORY_SCOPE_AGENT);
      if (vv != 0u) break;
      __builtin_amdgcn_s_sleep(2);
    }
    shm[0] = vv;
  }
  __syncthreads();
  const unsigned v = shm[0];
  __syncthreads();   // everyone has v before weight staging overwrites LDS

  if (v == 2u)        // mapping A verified: slab = bid&7 lives on one XCD
    run_loop<true >(x16, We, Wd, be, bd, h0, h1, out, stepFlags, stepGo, lds,
                    bid & 7, bid >> 3);
  else if (v == 3u)   // mapping B verified: slab = bid>>5 lives on one XCD
    run_loop<true >(x16, We, Wd, be, bd, h0, h1, out, stepFlags, stepGo, lds,
                    bid >> 5, bid & 31);
  else                // fallback: R6 LLC path (any block->XCD map)
    run_loop<false>(x16, We, Wd, be, bd, h0, h1, out, stepFlags, stepGo, lds,
                    bid & 7, bid >> 3);
}

// ---------------------------------------------------------------------------

extern "C" void kernel_launch(void* const* d_in, const int* in_sizes, int n_in,
                              void* d_out, int out_size, void* d_ws, size_t ws_size,
                              hipStream_t stream) {
  (void)in_sizes; (void)n_in; (void)out_size; (void)ws_size;
  const float* x   = (const float*)d_in[0];
  const float* Wih = (const float*)d_in[1];
  const float* Whh = (const float*)d_in[2];
  const float* bih = (const float*)d_in[3];
  const float* bhh = (const float*)d_in[4];
  const float* Wo  = (const float*)d_in[5];
  const float* bo  = (const float*)d_in[6];
  float* out = (float*)d_out;

  char* ws = (char*)d_ws;
  size_t off = 0;
  auto alloc = [&](size_t bytes) {
    char* p = ws + off;
    off += (bytes + 255) & ~(size_t)255;
    return p;
  };
  f16*   x16 = (f16*)  alloc((size_t)T_*B_*I_*2);
  f16*   hA  = (f16*)  alloc((size_t)B_*H_*2);
  f16*   hB  = (f16*)  alloc((size_t)B_*H_*2);
  f16*   We  = (f16*)  alloc((size_t)128*18*512*2);
  f16*   Wd  = (f16*)  alloc((size_t)160*16*512*2);
  float* Wf  = (float*)alloc((size_t)1536*512*4);
  float* be  = (float*)alloc(2048*4);
  float* bd  = (float*)alloc(2560*4);
  float* bf  = (float*)alloc(1536*4);
  size_t sync_base = off;
  unsigned* stepFlags = (unsigned*)alloc(256*64);  // (bm*32+g)*16, 64B padded
  unsigned* stepGo    = (unsigned*)alloc(8*64);
  unsigned* xcds      = (unsigned*)alloc(256*4);
  unsigned* verdict   = (unsigned*)alloc(64);
  size_t sync_bytes = off - sync_base;

  hipMemsetAsync(ws + sync_base, 0, sync_bytes, stream);
  hipLaunchKernelGGL(k_zero_h,   dim3((B_*H_+255)/256),    dim3(256), 0, stream, hA);
  hipLaunchKernelGGL(k_cvt_x,    dim3((T_*B_*I_+255)/256), dim3(256), 0, stream, x, x16);
  hipLaunchKernelGGL(k_fuse,     dim3(1536*512/256),       dim3(256), 0, stream, Wo, Wih, Wf);
  hipLaunchKernelGGL(k_bf,       dim3(6),                  dim3(256), 0, stream, bo, Wih, bf);
  hipLaunchKernelGGL(k_pack_enc, dim3(128*18*512/256),     dim3(256), 0, stream, Whh, Wih, We);
  hipLaunchKernelGGL(k_pack_dec, dim3(160*16*512/256),     dim3(256), 0, stream, Whh, Wo, Wf, Wd);
  hipLaunchKernelGGL(k_bias_enc, dim3(8),                  dim3(256), 0, stream, bih, bhh, be);
  hipLaunchKernelGGL(k_bias_dec, dim3(10),                 dim3(256), 0, stream, bih, bhh, bo, bf, bd);

  hipLaunchKernelGGL(k_persist, dim3(NBLK), dim3(256), 0, stream,
                     x16, We, Wd, be, bd, hA, hB, out,
                     stepFlags, stepGo, xcds, verdict);
}

// Round 11
// 1903.275 us; speedup vs baseline: 6.6255x; 1.1707x over previous
//
#include <hip/hip_runtime.h>

typedef _Float16 f16;
typedef _Float16 f16x8 __attribute__((ext_vector_type(8)));
typedef float f32x4 __attribute__((ext_vector_type(4)));

#define B_ 512
#define T_ 128
#define I_ 64
#define H_ 512
#define O_ 64
#define L_ 300
#define OUTSTR (L_*O_)
#define NBLK 256

// ---------------------------------------------------------------------------
// Prologue kernels (verified R0/R1/R3). Packed B layout (MFMA 16x16x32 f16):
//   flat = ((ntile_global*KSTEPS + kstep)*64 + lane)*8 + elem
//   value = W[k][col], k = kstep*32 + (lane>>4)*8 + elem, col = lane&15
// ---------------------------------------------------------------------------

__global__ void k_zero_h(f16* h) {
  int i = blockIdx.x*256 + threadIdx.x;
  if (i < B_*H_) h[i] = (f16)0.f;
}

__global__ void k_cvt_x(const float* __restrict__ x, f16* __restrict__ x16) {
  int p = blockIdx.x*256 + threadIdx.x;
  if (p >= T_*B_*I_) return;
  int i = p & 63, b = (p >> 6) & 511, t = p >> 15;
  x16[p] = (f16)x[((size_t)b*T_ + t)*I_ + i];
}

__global__ void k_fuse(const float* __restrict__ Wo, const float* __restrict__ Wih,
                       float* __restrict__ Wf) {
  int p = blockIdx.x*256 + threadIdx.x;
  if (p >= 1536*512) return;
  int k = p & 511, j3 = p >> 9;
  float s = 0.f;
  for (int o = 0; o < 64; ++o) s += Wo[(size_t)o*H_ + k] * Wih[(size_t)j3*I_ + o];
  Wf[p] = s;
}

__global__ void k_bf(const float* __restrict__ bo, const float* __restrict__ Wih,
                     float* __restrict__ bf) {
  int j3 = blockIdx.x*256 + threadIdx.x;
  if (j3 >= 1536) return;
  float s = 0.f;
  for (int o = 0; o < 64; ++o) s += bo[o]*Wih[(size_t)j3*I_ + o];
  bf[j3] = s;
}

__global__ void k_pack_enc(const float* __restrict__ Whh, const float* __restrict__ Wih,
                           f16* __restrict__ We) {
  int p = blockIdx.x*256 + threadIdx.x;
  if (p >= 128*18*512) return;
  int i = p & 7, l = (p >> 3) & 63, ks = (p >> 9) % 18, ntg = p / (18*512);
  int g = ntg >> 2, nti = ntg & 3, c = l & 15;
  int j = g*16 + c, k = ks*32 + ((l>>4)<<3) + i;
  float v = 0.f;
  if (nti == 0)      v = (k < 512) ? Whh[(size_t)j*H_ + k]        : Wih[(size_t)j*I_ + (k-512)];
  else if (nti == 1) v = (k < 512) ? Whh[(size_t)(512+j)*H_ + k]  : Wih[(size_t)(512+j)*I_ + (k-512)];
  else if (nti == 2) v = (k < 512) ? Whh[(size_t)(1024+j)*H_ + k] : 0.f;
  else               v = (k >= 512)? Wih[(size_t)(1024+j)*I_ + (k-512)] : 0.f;
  We[p] = (f16)v;
}

__global__ void k_pack_dec(const float* __restrict__ Whh, const float* __restrict__ Wo,
                           const float* __restrict__ Wf, f16* __restrict__ Wd) {
  int p = blockIdx.x*256 + threadIdx.x;
  if (p >= 160*16*512) return;
  int i = p & 7, l = (p >> 3) & 63, ks = (p >> 9) & 15, ntg = p >> 13;
  int g = ntg/5, nti = ntg%5, c = l & 15;
  int j = g*16 + c, k = ks*32 + ((l>>4)<<3) + i;
  float v;
  if (nti == 0)      v = Whh[(size_t)j*H_+k]       + Wf[(size_t)j*512 + k];
  else if (nti == 1) v = Whh[(size_t)(512+j)*H_+k] + Wf[(size_t)(512+j)*512 + k];
  else if (nti == 2) v = Whh[(size_t)(1024+j)*H_+k];
  else if (nti == 3) v = Wf[(size_t)(1024+j)*512 + k];
  else               v = (c < 2) ? Wo[(size_t)(2*g+c)*H_ + k] : 0.f;
  Wd[p] = (f16)v;
}

__global__ void k_bias_enc(const float* __restrict__ bih, const float* __restrict__ bhh,
                           float* __restrict__ be) {
  int p = blockIdx.x*256 + threadIdx.x;
  if (p >= 2048) return;
  int c = p & 15, ntg = p >> 4, g = ntg >> 2, nti = ntg & 3, j = g*16 + c;
  float v;
  if (nti == 0)      v = bih[j] + bhh[j];
  else if (nti == 1) v = bih[512+j] + bhh[512+j];
  else if (nti == 2) v = bhh[1024+j];
  else               v = bih[1024+j];
  be[p] = v;
}

__global__ void k_bias_dec(const float* __restrict__ bih, const float* __restrict__ bhh,
                           const float* __restrict__ bo, const float* __restrict__ bf,
                           float* __restrict__ bd) {
  int p = blockIdx.x*256 + threadIdx.x;
  if (p >= 2560) return;
  int c = p & 15, ntg = p >> 4, g = ntg/5, nti = ntg%5, j = g*16 + c;
  float v;
  if (nti == 0)      v = bih[j] + bhh[j] + bf[j];
  else if (nti == 1) v = bih[512+j] + bhh[512+j] + bf[512+j];
  else if (nti == 2) v = bhh[1024+j];
  else if (nti == 3) v = bih[1024+j] + bf[1024+j];
  else               v = (c < 2) ? bo[2*g+c] : 0.f;
  bd[p] = v;
}

// ---------------------------------------------------------------------------
// R10 = R8 with ONE change: fast-path barrier is ONE-ROUND (wave0 of every
// block polls its slab's 32 flags directly with sc0 sc1 -- the poll flavor
// proven coherent in R3/R6/R8). Removes the leader round trip + go poll.
// HW rules learned: sc0-only loads may be served from stale L1 when polled
// (R2/R7/R9 hangs) -> POLLS ALWAYS sc0 sc1; sc0 stores+streamed sc0 loads
// are XCD-L2-coherent for data (R8 PASS, hbm collapse).
// Fallback path keeps the R6 two-round LLC barrier verbatim.
// ---------------------------------------------------------------------------

__device__ __forceinline__ float sigmoidf_(float x){ return 1.f/(1.f + __expf(-x)); }
__device__ __forceinline__ float tanhf_(float x){ return 1.f - 2.f/(__expf(2.f*x) + 1.f); }

template<bool FA>
__device__ __forceinline__ f16x8 ldA(const f16* p) {     // coherent 16B load
  f16x8 r;
  if (FA) asm volatile("global_load_dwordx4 %0, %1, off sc0"     : "=&v"(r) : "v"(p));
  else    asm volatile("global_load_dwordx4 %0, %1, off sc0 sc1" : "=&v"(r) : "v"(p));
  return r;
}
__device__ __forceinline__ f16x8 ldP(const f16* p) {     // read-only (x16), cached
  f16x8 r;
  asm volatile("global_load_dwordx4 %0, %1, off" : "=&v"(r) : "v"(p));
  return r;
}
template<bool FA>
__device__ __forceinline__ void stH(f16* p, f16 h) {     // write-through 2B store
  unsigned b = (unsigned)__builtin_bit_cast(unsigned short, h);
  if (FA) asm volatile("global_store_short %0, %1, off sc0"     :: "v"(p), "v"(b) : "memory");
  else    asm volatile("global_store_short %0, %1, off sc0 sc1" :: "v"(p), "v"(b) : "memory");
}
// Single full drain before MFMA consumption (R3/R6-proven).
__device__ __forceinline__ void vwait0() {
  asm volatile("s_waitcnt vmcnt(0)" ::: "memory");
  __builtin_amdgcn_sched_barrier(0);
}

// FALLBACK per-slab barrier: two-round LLC, compiler atomics (R6/R8-proven).
__device__ __forceinline__ void sbar_llc(unsigned* __restrict__ flags,
                                         unsigned* __restrict__ go,
                                         int bm, int g, unsigned tgt) {
  asm volatile("s_waitcnt vmcnt(0)" ::: "memory");
  __syncthreads();
  const int tid = threadIdx.x;
  if (g == 0) {
    if (tid < 64) {
      if (tid == 0)
        __hip_atomic_store(&flags[(bm*32)*16], tgt, __ATOMIC_RELAXED,
                           __HIP_MEMORY_SCOPE_AGENT);
      unsigned v;
      do {
        v = __hip_atomic_load(&flags[(bm*32 + (tid & 31))*16], __ATOMIC_RELAXED,
                              __HIP_MEMORY_SCOPE_AGENT);
      } while (!__all(v >= tgt));
      if (tid == 0)
        __hip_atomic_store(&go[bm*16], tgt, __ATOMIC_RELAXED,
                           __HIP_MEMORY_SCOPE_AGENT);
    }
  } else {
    if (tid == 0) {
      __hip_atomic_store(&flags[(bm*32 + g)*16], tgt, __ATOMIC_RELAXED,
                         __HIP_MEMORY_SCOPE_AGENT);
      while (__hip_atomic_load(&go[bm*16], __ATOMIC_RELAXED,
                               __HIP_MEMORY_SCOPE_AGENT) < tgt)
        __builtin_amdgcn_s_sleep(2);
    }
  }
  __syncthreads();
  __builtin_amdgcn_sched_barrier(0);
}

// FAST per-slab barrier: ONE ROUND. Arrive: tid0 sc0sc1 flag store. Wait:
// wave 0 polls all 32 slab flags (lane = tid&31) with sc0 sc1 loads.
// flag==t implies that block's step-t reads AND stores are drained (vmcnt(0)
// precedes arrive), so seeing all 32 flags >= t makes overwriting the
// t-input buffer safe. No leader, no go line, no sleep.
__device__ __forceinline__ void sbar_1r(unsigned* __restrict__ flags,
                                        int bm, int g, unsigned tgt) {
  asm volatile("s_waitcnt vmcnt(0)" ::: "memory");  // h stores acked
  __syncthreads();                                  // all 4 waves drained
  if (threadIdx.x < 64) {
    if (threadIdx.x == 0) {
      unsigned* fp = flags + (bm*32 + g)*16;
      asm volatile("global_store_dword %0, %1, off sc0 sc1"
                   :: "v"(fp), "v"(tgt) : "memory");
    }
    const unsigned* pp = flags + (bm*32 + (threadIdx.x & 31))*16;
    for (;;) {
      unsigned v;
      asm volatile("global_load_dword %0, %1, off sc0 sc1\n\ts_waitcnt vmcnt(0)"
                   : "=&v"(v) : "v"(pp) : "memory");
      if (__ballot(v >= tgt) == ~0ull) break;
    }
  }
  __syncthreads();
  __builtin_amdgcn_sched_barrier(0);
}

#define MFMA16(a,b,acc) __builtin_amdgcn_mfma_f32_16x16x32_f16(a, b, acc, 0, 0, 0)

template<bool FA>
__device__ __forceinline__ void run_loop(
    const f16* __restrict__ x16, const f16* __restrict__ We,
    const f16* __restrict__ Wd, const float* __restrict__ be,
    const float* __restrict__ bd, f16* __restrict__ h0, f16* __restrict__ h1,
    float* __restrict__ out, unsigned* __restrict__ flags,
    unsigned* __restrict__ go, f16* lds, int bm, int g) {
  const int tid = threadIdx.x, w = tid >> 6, lane = tid & 63;
  const int c = lane & 15, rq = lane >> 4;
  const int row0 = bm*64 + w*16 + c;       // A-fragment row
  const int rowb = bm*64 + w*16 + rq*4;    // C/D row base
  const int j = g*16 + c;

  // ---- encoder: stage K=512 h-part weights to LDS once; x-part in regs ----
  for (int it = 0; it < 16; ++it) {
    int idx = it*256 + tid;
    int nt = idx >> 10, r = idx & 1023;
    *(f16x8*)((char*)lds + (size_t)idx*16) =
        *(const f16x8*)((const char*)We + (size_t)(g*4+nt)*18432 + (size_t)r*16);
  }
  f16x8 bx0,bx1,bx2,bx3,bx4,bx5,bx6,bx7;
  {
    const char* base = (const char*)We + (size_t)lane*16 + 16*1024;
    bx0 = *(const f16x8*)(base + (size_t)(g*4+0)*18432);
    bx1 = *(const f16x8*)(base + (size_t)(g*4+1)*18432);
    bx2 = *(const f16x8*)(base + (size_t)(g*4+2)*18432);
    bx3 = *(const f16x8*)(base + (size_t)(g*4+3)*18432);
    bx4 = *(const f16x8*)(base + (size_t)(g*4+0)*18432 + 1024);
    bx5 = *(const f16x8*)(base + (size_t)(g*4+1)*18432 + 1024);
    bx6 = *(const f16x8*)(base + (size_t)(g*4+2)*18432 + 1024);
    bx7 = *(const f16x8*)(base + (size_t)(g*4+3)*18432 + 1024);
  }
  float br = be[(g*4+0)*16+c], bz = be[(g*4+1)*16+c];
  float bh = be[(g*4+2)*16+c], bi = be[(g*4+3)*16+c];
  float hprev[4] = {0.f, 0.f, 0.f, 0.f};   // h_in[rowb+i][j], owned by THIS
                                           // thread (h0 starts zeroed)
  __syncthreads();

  unsigned s = 0;   // global step index 0..426
  for (int t = 0; t < T_; ++t, ++s) {
    const f16* hin  = (t & 1) ? h1 : h0;
    f16*       hout = (t & 1) ? h0 : h1;
    const f16* xt = x16 + (size_t)t*B_*I_;
    f16x8 ha[16];
    #pragma unroll
    for (int ks = 0; ks < 16; ++ks)
      ha[ks] = ldA<FA>(hin + (size_t)row0*H_ + ks*32 + (rq<<3));
    f16x8 ax = ldP(xt + (size_t)row0*I_ + (rq<<3));
    f16x8 ay = ldP(xt + (size_t)row0*I_ + 32 + (rq<<3));
    vwait0();
    f32x4 a0={},a1={},a2={},a3={};
    #pragma unroll
    for (int ks = 0; ks < 16; ++ks) {
      a0 = MFMA16(ha[ks], *(const f16x8*)(lds + (0*16+ks)*512 + lane*8), a0);
      a1 = MFMA16(ha[ks], *(const f16x8*)(lds + (1*16+ks)*512 + lane*8), a1);
      a2 = MFMA16(ha[ks], *(const f16x8*)(lds + (2*16+ks)*512 + lane*8), a2);
      a3 = MFMA16(ha[ks], *(const f16x8*)(lds + (3*16+ks)*512 + lane*8), a3);
    }
    a0 = MFMA16(ax, bx0, a0); a1 = MFMA16(ax, bx1, a1);
    a2 = MFMA16(ax, bx2, a2); a3 = MFMA16(ax, bx3, a3);
    a0 = MFMA16(ay, bx4, a0); a1 = MFMA16(ay, bx5, a1);
    a2 = MFMA16(ay, bx6, a2); a3 = MFMA16(ay, bx7, a3);
    #pragma unroll
    for (int i = 0; i < 4; ++i) {
      float r = sigmoidf_(a0[i] + br);
      float z = sigmoidf_(a1[i] + bz);
      float n = tanhf_((a3[i] + bi) + r*(a2[i] + bh));
      f16 hv = (f16)((1.f - z)*n + z*hprev[i]);
      stH<FA>(hout + (size_t)(rowb+i)*H_ + j, hv);
      hprev[i] = (float)hv;
    }
    if (FA) sbar_1r (flags, bm, g, s+1);
    else    sbar_llc(flags, go, bm, g, s+1);
  }

  // ---- decoder: restage gate ntiles; y-ntile in regs ----
  __syncthreads();
  for (int it = 0; it < 16; ++it) {
    int idx = it*256 + tid;
    int nt = idx >> 10, r = idx & 1023;
    *(f16x8*)((char*)lds + (size_t)idx*16) =
        *(const f16x8*)((const char*)Wd + (size_t)(g*5+nt)*16384 + (size_t)r*16);
  }
  f16x8 yb[16];
  #pragma unroll
  for (int ks = 0; ks < 16; ++ks)
    yb[ks] = *(const f16x8*)((const char*)Wd + (size_t)(g*5+4)*16384
                             + (size_t)ks*1024 + (size_t)lane*16);
  float dr = bd[(g*5+0)*16+c], dz = bd[(g*5+1)*16+c];
  float dh = bd[(g*5+2)*16+c], di = bd[(g*5+3)*16+c], dy = bd[(g*5+4)*16+c];
  __syncthreads();

  for (int d = 0; d < L_-1; ++d, ++s) {
    const f16* hin  = (d & 1) ? h1 : h0;
    f16*       hout = (d & 1) ? h0 : h1;
    f16x8 ha[16];
    #pragma unroll
    for (int ks = 0; ks < 16; ++ks)
      ha[ks] = ldA<FA>(hin + (size_t)row0*H_ + ks*32 + (rq<<3));
    vwait0();
    f32x4 a0={},a1={},a2={},a3={},a4={};
    #pragma unroll
    for (int ks = 0; ks < 16; ++ks) {
      a0 = MFMA16(ha[ks], *(const f16x8*)(lds + (0*16+ks)*512 + lane*8), a0);
      a1 = MFMA16(ha[ks], *(const f16x8*)(lds + (1*16+ks)*512 + lane*8), a1);
      a2 = MFMA16(ha[ks], *(const f16x8*)(lds + (2*16+ks)*512 + lane*8), a2);
      a3 = MFMA16(ha[ks], *(const f16x8*)(lds + (3*16+ks)*512 + lane*8), a3);
      a4 = MFMA16(ha[ks], yb[ks], a4);
    }
    float* yo = out + (size_t)d*O_;
    #pragma unroll
    for (int i = 0; i < 4; ++i) {
      float r = sigmoidf_(a0[i] + dr);
      float z = sigmoidf_(a1[i] + dz);
      float n = tanhf_((a3[i] + di) + r*(a2[i] + dh));
      f16 hv = (f16)((1.f - z)*n + z*hprev[i]);
      stH<FA>(hout + (size_t)(rowb+i)*H_ + j, hv);
      hprev[i] = (float)hv;
      if (c < 2) yo[(size_t)(rowb+i)*OUTSTR + 2*g + c] = a4[i] + dy;
    }
    if (FA) sbar_1r (flags, bm, g, s+1);
    else    sbar_llc(flags, go, bm, g, s+1);
  }

  // ---- final y projection from h1 (written at d=298; slab-local) ----
  {
    f16x8 ha[16];
    #pragma unroll
    for (int ks = 0; ks < 16; ++ks)
      ha[ks] = ldA<FA>(h1 + (size_t)row0*H_ + ks*32 + (rq<<3));
    vwait0();
    f32x4 a4 = {};
    #pragma unroll
    for (int ks = 0; ks < 16; ++ks) a4 = MFMA16(ha[ks], yb[ks], a4);
    if (c < 2) {
      #pragma unroll
      for (int i = 0; i < 4; ++i)
        out[(size_t)(rowb+i)*OUTSTR + (size_t)(L_-1)*O_ + 2*g + c] = a4[i] + dy;
    }
  }
}

__global__ __launch_bounds__(256, 1) void k_persist(
    const f16* __restrict__ x16, const f16* __restrict__ We,
    const f16* __restrict__ Wd, const float* __restrict__ be,
    const float* __restrict__ bd, f16* __restrict__ h0, f16* __restrict__ h1,
    float* __restrict__ out, unsigned* __restrict__ stepFlags,
    unsigned* __restrict__ stepGo, unsigned* __restrict__ xcds,
    unsigned* __restrict__ verdict) {
  __shared__ f16 lds[32768];
  const int tid = threadIdx.x, bid = blockIdx.x;

  // ---- every block unconditionally publishes XCC_ID|8 (nonzero marker) ----
  if (tid == 0) {
    unsigned xcc;
    asm volatile("s_getreg_b32 %0, hwreg(HW_REG_XCC_ID)" : "=s"(xcc));
    __hip_atomic_store(&xcds[bid], (xcc & 7u) | 8u, __ATOMIC_RELAXED,
                       __HIP_MEMORY_SCOPE_AGENT);
  }
  // ---- block 0: wait all published, decide, publish verdict (acyclic) ----
  if (bid == 0 && tid < 64) {
    for (;;) {
      int ready = 1;
      for (int k2 = 0; k2 < 4; ++k2)
        ready &= (__hip_atomic_load(&xcds[tid*4 + k2], __ATOMIC_RELAXED,
                                    __HIP_MEMORY_SCOPE_AGENT) >= 8u);
      if (__ballot(ready != 0) == ~0ull) break;
      __builtin_amdgcn_s_sleep(2);
    }
    int okA = 1, okB = 1;
    for (int k2 = 0; k2 < 4; ++k2) {
      int b2 = tid*4 + k2;
      unsigned xv = __hip_atomic_load(&xcds[b2],         __ATOMIC_RELAXED, __HIP_MEMORY_SCOPE_AGENT);
      unsigned ra = __hip_atomic_load(&xcds[b2 & 7],     __ATOMIC_RELAXED, __HIP_MEMORY_SCOPE_AGENT);
      unsigned rb = __hip_atomic_load(&xcds[(b2>>5)<<5], __ATOMIC_RELAXED, __HIP_MEMORY_SCOPE_AGENT);
      okA &= (xv == ra); okB &= (xv == rb);
    }
    bool allA = (__ballot(okA != 0) == ~0ull);
    bool allB = (__ballot(okB != 0) == ~0ull);
    if (tid == 0)
      __hip_atomic_store(verdict, allA ? 2u : (allB ? 3u : 1u),
                         __ATOMIC_RELAXED, __HIP_MEMORY_SCOPE_AGENT);
  }
  // ---- all blocks poll the single verdict (block 0 only waits on xcds,
  //      which are published unconditionally -> no circular dependency) ----
  volatile unsigned* shm = (volatile unsigned*)lds;
  if (tid == 0) {
    unsigned vv;
    for (;;) {
      vv = __hip_atomic_load(verdict, __ATOMIC_RELAXED, __HIP_MEMORY_SCOPE_AGENT);
      if (vv != 0u) break;
      __builtin_amdgcn_s_sleep(2);
    }
    shm[0] = vv;
  }
  __syncthreads();
  const unsigned v = shm[0];
  __syncthreads();   // everyone has v before weight staging overwrites LDS

  if (v == 2u)        // mapping A verified: slab = bid&7 lives on one XCD
    run_loop<true >(x16, We, Wd, be, bd, h0, h1, out, stepFlags, stepGo, lds,
                    bid & 7, bid >> 3);
  else if (v == 3u)   // mapping B verified: slab = bid>>5 lives on one XCD
    run_loop<true >(x16, We, Wd, be, bd, h0, h1, out, stepFlags, stepGo, lds,
                    bid >> 5, bid & 31);
  else                // fallback: R6 LLC path (any block->XCD map)
    run_loop<false>(x16, We, Wd, be, bd, h0, h1, out, stepFlags, stepGo, lds,
                    bid & 7, bid >> 3);
}

// ---------------------------------------------------------------------------

extern "C" void kernel_launch(void* const* d_in, const int* in_sizes, int n_in,
                              void* d_out, int out_size, void* d_ws, size_t ws_size,
                              hipStream_t stream) {
  (void)in_sizes; (void)n_in; (void)out_size; (void)ws_size;
  const float* x   = (const float*)d_in[0];
  const float* Wih = (const float*)d_in[1];
  const float* Whh = (const float*)d_in[2];
  const float* bih = (const float*)d_in[3];
  const float* bhh = (const float*)d_in[4];
  const float* Wo  = (const float*)d_in[5];
  const float* bo  = (const float*)d_in[6];
  float* out = (float*)d_out;

  char* ws = (char*)d_ws;
  size_t off = 0;
  auto alloc = [&](size_t bytes) {
    char* p = ws + off;
    off += (bytes + 255) & ~(size_t)255;
    return p;
  };
  f16*   x16 = (f16*)  alloc((size_t)T_*B_*I_*2);
  f16*   hA  = (f16*)  alloc((size_t)B_*H_*2);
  f16*   hB  = (f16*)  alloc((size_t)B_*H_*2);
  f16*   We  = (f16*)  alloc((size_t)128*18*512*2);
  f16*   Wd  = (f16*)  alloc((size_t)160*16*512*2);
  float* Wf  = (float*)alloc((size_t)1536*512*4);
  float* be  = (float*)alloc(2048*4);
  float* bd  = (float*)alloc(2560*4);
  float* bf  = (float*)alloc(1536*4);
  size_t sync_base = off;
  unsigned* stepFlags = (unsigned*)alloc(256*64);  // (bm*32+g)*16, 64B padded
  unsigned* stepGo    = (unsigned*)alloc(8*64);
  unsigned* xcds      = (unsigned*)alloc(256*4);
  unsigned* verdict   = (unsigned*)alloc(64);
  size_t sync_bytes = off - sync_base;

  hipMemsetAsync(ws + sync_base, 0, sync_bytes, stream);
  hipLaunchKernelGGL(k_zero_h,   dim3((B_*H_+255)/256),    dim3(256), 0, stream, hA);
  hipLaunchKernelGGL(k_cvt_x,    dim3((T_*B_*I_+255)/256), dim3(256), 0, stream, x, x16);
  hipLaunchKernelGGL(k_fuse,     dim3(1536*512/256),       dim3(256), 0, stream, Wo, Wih, Wf);
  hipLaunchKernelGGL(k_bf,       dim3(6),                  dim3(256), 0, stream, bo, Wih, bf);
  hipLaunchKernelGGL(k_pack_enc, dim3(128*18*512/256),     dim3(256), 0, stream, Whh, Wih, We);
  hipLaunchKernelGGL(k_pack_dec, dim3(160*16*512/256),     dim3(256), 0, stream, Whh, Wo, Wf, Wd);
  hipLaunchKernelGGL(k_bias_enc, dim3(8),                  dim3(256), 0, stream, bih, bhh, be);
  hipLaunchKernelGGL(k_bias_dec, dim3(10),                 dim3(256), 0, stream, bih, bhh, bo, bf, bd);

  hipLaunchKernelGGL(k_persist, dim3(NBLK), dim3(256), 0, stream,
                     x16, We, Wd, be, bd, hA, hB, out,
                     stepFlags, stepGo, xcds, verdict);
}